// Round 15
// baseline (460.274 us; speedup 1.0000x reference)
//
#include <hip/hip_runtime.h>
#include <hip/hip_bf16.h>

typedef unsigned short u16;
typedef unsigned char u8;
typedef short short8 __attribute__((ext_vector_type(8)));
typedef float floatx4 __attribute__((ext_vector_type(4)));
typedef float floatx2 __attribute__((ext_vector_type(2)));

__device__ __forceinline__ float b2f(u16 u) {
    unsigned v = ((unsigned)u) << 16;
    float f;
    __builtin_memcpy(&f, &v, 4);
    return f;
}
__device__ __forceinline__ float b2f_lo(unsigned w) { return b2f((u16)(w & 0xffffu)); }
__device__ __forceinline__ float b2f_hi(unsigned w) { return b2f((u16)(w >> 16)); }
__device__ __forceinline__ u16 f2b(float f) {
    unsigned u;
    __builtin_memcpy(&u, &f, 4);
    u = u + 0x7fffu + ((u >> 16) & 1u);
    return (u16)(u >> 16);
}
__device__ __forceinline__ unsigned pack2(float a, float b) {
    return (unsigned)f2b(a) | ((unsigned)f2b(b) << 16);
}
__device__ __forceinline__ float loadp(const void* p, int i, int f) {
    return f ? ((const float*)p)[i] : b2f(((const u16*)p)[i]);
}
__device__ __forceinline__ u8 f2e4m3(float v) {
    int r = __builtin_amdgcn_cvt_pk_fp8_f32(v, v, 0, false);
    return (u8)(r & 0xff);
}
// accumulate 16 fp8 values (one uint4) into a[16]
__device__ __forceinline__ void acc16_fp8(float* a, uint4 p) {
    floatx2 f;
    f = __builtin_amdgcn_cvt_pk_f32_fp8((int)p.x, false); a[0] += f[0];  a[1] += f[1];
    f = __builtin_amdgcn_cvt_pk_f32_fp8((int)p.x, true);  a[2] += f[0];  a[3] += f[1];
    f = __builtin_amdgcn_cvt_pk_f32_fp8((int)p.y, false); a[4] += f[0];  a[5] += f[1];
    f = __builtin_amdgcn_cvt_pk_f32_fp8((int)p.y, true);  a[6] += f[0];  a[7] += f[1];
    f = __builtin_amdgcn_cvt_pk_f32_fp8((int)p.z, false); a[8] += f[0];  a[9] += f[1];
    f = __builtin_amdgcn_cvt_pk_f32_fp8((int)p.z, true);  a[10] += f[0]; a[11] += f[1];
    f = __builtin_amdgcn_cvt_pk_f32_fp8((int)p.w, false); a[12] += f[0]; a[13] += f[1];
    f = __builtin_amdgcn_cvt_pk_f32_fp8((int)p.w, true);  a[14] += f[0]; a[15] += f[1];
}

// ---------------- dtype sniffing ----------------
__global__ void sniff_kernel(const unsigned* __restrict__ xw, const int* __restrict__ eiw,
                             int* __restrict__ flags) {
    __shared__ int s_fp32, s_i64;
    if (threadIdx.x == 0) { s_fp32 = 0; s_i64 = 1; }
    __syncthreads();
    int t = threadIdx.x;  // 256 threads
    unsigned w = xw[t];
    float lo = b2f_lo(w);
    if (!(fabsf(lo) <= 64.0f)) atomicOr(&s_fp32, 1);   // also catches NaN
    if (eiw[2 * t + 1] != 0) atomicAnd(&s_i64, 0);
    __syncthreads();
    if (t == 0) { flags[0] = s_fp32; flags[1] = s_i64; }
}

// ---------------- input conversion (bf16 + fp8 shadow) ----------------
__global__ void cvt_x_kernel(const void* __restrict__ x, u16* __restrict__ xb,
                             u16* __restrict__ x8,   // fp8 pairs stored as u16
                             const int* __restrict__ flags, int nPairs) {
    int f = flags[0];
    int i = blockIdx.x * 256 + threadIdx.x;
    if (i >= nPairs) return;
    float lo, hi;
    if (f) {
        float2 v = ((const float2*)x)[i];
        lo = v.x; hi = v.y;
        ((unsigned*)xb)[i] = pack2(lo, hi);
    } else {
        unsigned w = ((const unsigned*)x)[i];
        lo = b2f_lo(w); hi = b2f_hi(w);
        ((unsigned*)xb)[i] = w;
    }
    int r = __builtin_amdgcn_cvt_pk_fp8_f32(lo, hi, 0, false);
    x8[i] = (u16)(r & 0xffff);
}

// ---------------- fused parameter prep (one launch) ----------------
__global__ void prep_all_kernel(const void* Wl1, const void* Wr1, u16* __restrict__ Wcat1,
                                const void* Wl2, const void* Wr2, u16* __restrict__ Wcat2,
                                const void* Wl3, const void* Wr3, u16* __restrict__ Wcat3,
                                const void* We1, u16* __restrict__ Web,
                                const void* g1, const void* b1, const void* bl1,
                                float* __restrict__ al1, float* __restrict__ bt1,
                                const void* g2, const void* b2, const void* bl2,
                                float* __restrict__ al2, float* __restrict__ bt2,
                                const void* bl3,
                                float* __restrict__ al3, float* __restrict__ bt3,
                                const void* be1, const void* We2, const void* be2,
                                float* __restrict__ dparams,
                                const int* __restrict__ flags) {
    int f = flags[0];
    int idx = blockIdx.x * 256 + threadIdx.x;
    if (idx < 16384) {
        int k = idx >> 7, n = idx & 127;           // Wl1/Wr1: [k=128][n=128]
        Wcat1[n * 256 + k]       = f ? f2b(((const float*)Wl1)[idx]) : ((const u16*)Wl1)[idx];
        Wcat1[n * 256 + 128 + k] = f ? f2b(((const float*)Wr1)[idx]) : ((const u16*)Wr1)[idx];
    } else if (idx < 32768) {
        int i = idx - 16384;
        int k = i >> 7, n = i & 127;
        Wcat2[n * 256 + k]       = f ? f2b(((const float*)Wl2)[i]) : ((const u16*)Wl2)[i];
        Wcat2[n * 256 + 128 + k] = f ? f2b(((const float*)Wr2)[i]) : ((const u16*)Wr2)[i];
    } else if (idx < 49152) {
        int i = idx - 32768;
        int k = i >> 7, n = i & 127;               // combined [k=128][n=128], n<64 Wl3 else Wr3
        const void* src = (n < 64) ? Wl3 : Wr3;
        int j = k * 64 + (n & 63);
        Wcat3[n * 128 + k] = f ? f2b(((const float*)src)[j]) : ((const u16*)src)[j];
    } else if (idx < 65536) {
        int i = idx - 49152;
        int k = i >> 7, n = i & 127;               // We1: [k=128][n=128]
        Web[n * 128 + k] = f ? f2b(((const float*)We1)[i]) : ((const u16*)We1)[i];
    } else {
        int i = idx - 65536;
        if (i < 128) {
            float s = loadp(g1, i, f) * rsqrtf(1.0f + 1e-5f);
            al1[i] = s;
            bt1[i] = loadp(bl1, i, f) * s + loadp(b1, i, f);
        } else if (i < 256) {
            int j = i - 128;
            float s = loadp(g2, j, f) * rsqrtf(1.0f + 1e-5f);
            al2[j] = s;
            bt2[j] = loadp(bl2, j, f) * s + loadp(b2, j, f);
        } else if (i < 384) {
            int j = i - 256;
            al3[j] = 1.0f;
            bt3[j] = (j < 64) ? 0.0f : loadp(bl3, j - 64, f);
        } else if (i < 512) {
            int j = i - 384;
            dparams[j] = loadp(be1, j, f);
            dparams[128 + j] = loadp(We2, j, f);
            if (j == 0) dparams[256] = loadp(be2, 0, f);
        }
    }
}

// ---------------- CSR build: two-level counting sort (no global atomics) ----------------
__device__ __forceinline__ int edge_at(const int* ei, long long idx, int i64) {
    return i64 ? ei[2 * idx] : ei[idx];
}

__global__ __launch_bounds__(256) void bucket_count_kernel(const int* __restrict__ ei,
                                                           int* __restrict__ blockhist,
                                                           int E, int EPB, int nbuckP, int nbuck,
                                                           const int* __restrict__ flags) {
    __shared__ int hist[1024];
    for (int i = threadIdx.x; i < nbuck; i += 256) hist[i] = 0;
    __syncthreads();
    int i64 = flags[1];
    int b = blockIdx.x;
    int lo = b * EPB, hi = min(lo + EPB, E);
    for (int e = lo + (int)threadIdx.x; e < hi; e += 256) {
        int d = edge_at(ei, (long long)E + e, i64);
        atomicAdd(&hist[d >> 7], 1);
    }
    __syncthreads();
    for (int k = threadIdx.x; k < nbuck; k += 256)
        blockhist[(size_t)b * nbuckP + k] = hist[k];
}

// looped 64-wide exclusive scan (over blocks b) with carry; strided reads, high TLP
__global__ __launch_bounds__(64) void colscan_kernel(int* __restrict__ blockhist,
                                                     int* __restrict__ coltot,
                                                     int B1, int nbuckP) {
    int k = blockIdx.x, l = threadIdx.x;
    int carry = 0;
    for (int base = 0; base < B1; base += 64) {
        int idx = base + l;
        int x = (idx < B1) ? blockhist[(size_t)idx * nbuckP + k] : 0;
        int s = x;
        #pragma unroll
        for (int off = 1; off < 64; off <<= 1) {
            int u = __shfl_up(s, off, 64);
            if (l >= off) s += u;
        }
        if (idx < B1) blockhist[(size_t)idx * nbuckP + k] = carry + s - x;
        carry += __shfl(s, 63, 64);
    }
    if (l == 0) coltot[k] = carry;
}

__global__ __launch_bounds__(1024) void base_scan_kernel(const int* __restrict__ coltot,
                                                         int* __restrict__ bucketbase,
                                                         int* __restrict__ rowptrN,
                                                         int nbuck, int E) {
    __shared__ int wsum[16];
    int t = threadIdx.x, lane = t & 63, w = t >> 6;
    int v = (t < nbuck) ? coltot[t] : 0;
    int inc = v;
    #pragma unroll
    for (int off = 1; off < 64; off <<= 1) {
        int u = __shfl_up(inc, off, 64);
        if (lane >= off) inc += u;
    }
    if (lane == 63) wsum[w] = inc;
    __syncthreads();
    int add = 0;
    for (int i = 0; i < w; ++i) add += wsum[i];
    if (t < nbuck) bucketbase[t] = add + inc - v;
    if (t == 0) rowptrN[0] = E;
}

__global__ __launch_bounds__(256) void bucket_scatter_kernel(const int* __restrict__ ei,
                                                             const int* __restrict__ bucketbase,
                                                             const int* __restrict__ blockhist,
                                                             unsigned* __restrict__ pairs,
                                                             int E, int EPB, int nbuckP, int nbuck,
                                                             const int* __restrict__ flags) {
    __shared__ int off[1024];
    int b = blockIdx.x;
    for (int k = threadIdx.x; k < nbuck; k += 256)
        off[k] = bucketbase[k] + blockhist[(size_t)b * nbuckP + k];
    __syncthreads();
    int i64 = flags[1];
    int lo = b * EPB, hi = min(lo + EPB, E);
    for (int e = lo + (int)threadIdx.x; e < hi; e += 256) {
        int s = edge_at(ei, e, i64);
        int d = edge_at(ei, (long long)E + e, i64);
        int slot = atomicAdd(&off[d >> 7], 1);
        pairs[slot] = (unsigned)s | ((unsigned)(d & 127) << 25);
    }
}

__global__ __launch_bounds__(256) void bucket_csr_kernel(const unsigned* __restrict__ pairs,
                                                         const int* __restrict__ bucketbase,
                                                         const int* __restrict__ coltot,
                                                         int* __restrict__ rowptr,
                                                         int* __restrict__ col, int N) {
    __shared__ unsigned pk[4096];
    __shared__ int hist[128], cur[128];
    int k = blockIdx.x, tid = threadIdx.x;
    if (tid < 128) hist[tid] = 0;
    __syncthreads();
    int base = bucketbase[k], cnt = coltot[k];
    int staged = min(cnt, 4096);
    for (int i = tid; i < cnt; i += 256) {
        unsigned pv = pairs[base + i];
        int j = (int)(pv >> 25);
        atomicAdd(&hist[j], 1);
        if (i < 4096) pk[i] = pv;
    }
    __syncthreads();
    if (tid < 64) {
        int x0 = hist[tid], x1 = hist[64 + tid];
        int s0 = x0;
        #pragma unroll
        for (int off = 1; off < 64; off <<= 1) {
            int u = __shfl_up(s0, off, 64);
            if (tid >= off) s0 += u;
        }
        int tot0 = __shfl(s0, 63, 64);
        int s1 = x1;
        #pragma unroll
        for (int off = 1; off < 64; off <<= 1) {
            int u = __shfl_up(s1, off, 64);
            if (tid >= off) s1 += u;
        }
        s1 += tot0;
        cur[tid] = s0 - x0;
        cur[64 + tid] = s1 - x1;
    }
    __syncthreads();
    int node0 = k << 7;
    if (tid < 128 && node0 + tid < N) rowptr[node0 + tid] = base + cur[tid];
    __syncthreads();
    for (int i = tid; i < staged; i += 256) {
        unsigned pv = pk[i];
        int slot = base + atomicAdd(&cur[pv >> 25], 1);
        col[slot] = (int)(pv & 0x1FFFFFFu);
    }
    for (int i = 4096 + tid; i < cnt; i += 256) {
        unsigned pv = pairs[base + i];
        int slot = base + atomicAdd(&cur[pv >> 25], 1);
        col[slot] = (int)(pv & 0x1FFFFFFu);
    }
}

// ---------------- fused layer-3 tail: z = mean_fp8(t8) + u ; write zbuf + d_out ----------------
__global__ __launch_bounds__(256) void agg_combine_kernel(const u8* __restrict__ T8,
                                                          const int* __restrict__ rowptr,
                                                          const int* __restrict__ col,
                                                          const u16* __restrict__ ubuf,
                                                          u16* __restrict__ zbuf,
                                                          void* __restrict__ dout,
                                                          int N, const int* __restrict__ flags) {
    constexpr int LPR = 4;           // 64 ch / 16
    constexpr int GPB = 64;
    int f = flags[0];
    int t = threadIdx.x;
    int g = t / LPR;
    int o = t % LPR;
    int u = blockIdx.x * GPB + g;
    if (u >= N) return;
    const uint4* Xv = (const uint4*)T8;
    int beg = rowptr[u], end = rowptr[u + 1];
    float a[16];
    #pragma unroll
    for (int i = 0; i < 16; ++i) a[i] = 0.f;
    int e = beg;
    for (; e + 8 <= end; e += 8) {
        uint4 p0 = Xv[(size_t)col[e]     * LPR + o];
        uint4 p1 = Xv[(size_t)col[e + 1] * LPR + o];
        uint4 p2 = Xv[(size_t)col[e + 2] * LPR + o];
        uint4 p3 = Xv[(size_t)col[e + 3] * LPR + o];
        uint4 p4 = Xv[(size_t)col[e + 4] * LPR + o];
        uint4 p5 = Xv[(size_t)col[e + 5] * LPR + o];
        uint4 p6 = Xv[(size_t)col[e + 6] * LPR + o];
        uint4 p7 = Xv[(size_t)col[e + 7] * LPR + o];
        acc16_fp8(a, p0); acc16_fp8(a, p1); acc16_fp8(a, p2); acc16_fp8(a, p3);
        acc16_fp8(a, p4); acc16_fp8(a, p5); acc16_fp8(a, p6); acc16_fp8(a, p7);
    }
    for (; e + 4 <= end; e += 4) {
        uint4 p0 = Xv[(size_t)col[e]     * LPR + o];
        uint4 p1 = Xv[(size_t)col[e + 1] * LPR + o];
        uint4 p2 = Xv[(size_t)col[e + 2] * LPR + o];
        uint4 p3 = Xv[(size_t)col[e + 3] * LPR + o];
        acc16_fp8(a, p0); acc16_fp8(a, p1); acc16_fp8(a, p2); acc16_fp8(a, p3);
    }
    for (; e < end; ++e) {
        uint4 p = Xv[(size_t)col[e] * LPR + o];
        acc16_fp8(a, p);
    }
    int deg = end - beg;
    float inv = (deg > 0) ? 1.0f / (float)deg : 0.0f;
    const uint4* uv = (const uint4*)(ubuf + (size_t)u * 64 + o * 16);
    uint4 u0 = uv[0], u1 = uv[1];
    float z[16];
    z[0] = a[0] * inv + b2f_lo(u0.x);  z[1] = a[1] * inv + b2f_hi(u0.x);
    z[2] = a[2] * inv + b2f_lo(u0.y);  z[3] = a[3] * inv + b2f_hi(u0.y);
    z[4] = a[4] * inv + b2f_lo(u0.z);  z[5] = a[5] * inv + b2f_hi(u0.z);
    z[6] = a[6] * inv + b2f_lo(u0.w);  z[7] = a[7] * inv + b2f_hi(u0.w);
    z[8] = a[8] * inv + b2f_lo(u1.x);  z[9] = a[9] * inv + b2f_hi(u1.x);
    z[10] = a[10] * inv + b2f_lo(u1.y); z[11] = a[11] * inv + b2f_hi(u1.y);
    z[12] = a[12] * inv + b2f_lo(u1.z); z[13] = a[13] * inv + b2f_hi(u1.z);
    z[14] = a[14] * inv + b2f_lo(u1.w); z[15] = a[15] * inv + b2f_hi(u1.w);
    uint4 zv0, zv1;
    zv0.x = pack2(z[0], z[1]);   zv0.y = pack2(z[2], z[3]);
    zv0.z = pack2(z[4], z[5]);   zv0.w = pack2(z[6], z[7]);
    zv1.x = pack2(z[8], z[9]);   zv1.y = pack2(z[10], z[11]);
    zv1.z = pack2(z[12], z[13]); zv1.w = pack2(z[14], z[15]);
    uint4* zo = (uint4*)(zbuf + (size_t)u * 64 + o * 16);
    zo[0] = zv0; zo[1] = zv1;
    if (f) {
        float* fo = (float*)dout + (size_t)u * 64 + o * 16;
        #pragma unroll
        for (int i = 0; i < 16; ++i) fo[i] = z[i];
    } else {
        uint4* bo = (uint4*)((u16*)dout + (size_t)u * 64 + o * 16);
        bo[0] = zv0; bo[1] = zv1;
    }
}

// ---------------- FUSED aggregate + SAGE GEMM (layers 1-2, K=256) ----------------
// Block = 64 nodes x 128 cols. Phase 1: stage root rows (LDS cols 128..255) and
// aggregate fp8 neighbor means in-register (4 thr/node x 32ch) -> LDS cols 0..127.
// Phase 2 (after ONE barrier): identical MFMA loop + epilogue; residual from LDS.
__global__ __launch_bounds__(256) void fused_agg_gemm_kernel(
    const u8* __restrict__ X8, const int* __restrict__ rowptr, const int* __restrict__ col,
    const u16* __restrict__ A2,                 // root features bf16 [N][128]
    const u16* __restrict__ WT,
    const float* __restrict__ alpha, const float* __restrict__ beta,
    int addRes, u16* __restrict__ out, int ldo, u16* __restrict__ outB,
    u8* __restrict__ out8, int ld8,
    int M, int relu) {
    constexpr int K = 256;
    constexpr int STRIDE = K + 8;
    constexpr int NK = K / 32;
    extern __shared__ u16 As[];                 // 64 x STRIDE
    int tid = threadIdx.x;
    int mBase = blockIdx.x * 64;
    int lane = tid & 63, w = tid >> 6;
    int q = lane >> 4, r = lane & 15;

    // ---- stage root rows into LDS cols 128..255 (coalesced; issued first) ----
    {
        int row = tid >> 2, cb = (tid & 3) * 8;
        int gr = mBase + row;
        #pragma unroll
        for (int j = 128; j < 256; j += 32) {
            int k = cb + j;
            short8 v = (short8){0, 0, 0, 0, 0, 0, 0, 0};
            if (gr < M) v = *(const short8*)(A2 + (size_t)gr * 128 + (k - 128));
            *(short8*)(&As[row * STRIDE + k]) = v;
        }
    }

    // ---- aggregate fp8 neighbor mean: 4 threads/node, each owns 32 channels ----
    {
        int g = tid >> 2, o = tid & 3;
        int gr = mBase + g;
        float a[32];
        #pragma unroll
        for (int i = 0; i < 32; ++i) a[i] = 0.f;
        int beg = 0, end = 0;
        if (gr < M) { beg = rowptr[gr]; end = rowptr[gr + 1]; }
        const uint4* Xv = (const uint4*)X8;
        int e = beg;
        for (; e + 4 <= end; e += 4) {
            size_t c0 = (size_t)col[e]     * 8 + o * 2;
            size_t c1 = (size_t)col[e + 1] * 8 + o * 2;
            size_t c2 = (size_t)col[e + 2] * 8 + o * 2;
            size_t c3 = (size_t)col[e + 3] * 8 + o * 2;
            uint4 p0a = Xv[c0], p0b = Xv[c0 + 1];
            uint4 p1a = Xv[c1], p1b = Xv[c1 + 1];
            uint4 p2a = Xv[c2], p2b = Xv[c2 + 1];
            uint4 p3a = Xv[c3], p3b = Xv[c3 + 1];
            acc16_fp8(a, p0a); acc16_fp8(a + 16, p0b);
            acc16_fp8(a, p1a); acc16_fp8(a + 16, p1b);
            acc16_fp8(a, p2a); acc16_fp8(a + 16, p2b);
            acc16_fp8(a, p3a); acc16_fp8(a + 16, p3b);
        }
        for (; e < end; ++e) {
            size_t c = (size_t)col[e] * 8 + o * 2;
            uint4 pa = Xv[c], pb = Xv[c + 1];
            acc16_fp8(a, pa); acc16_fp8(a + 16, pb);
        }
        int deg = end - beg;
        float inv = (deg > 0) ? 1.0f / (float)deg : 0.0f;
        // write 32 bf16 means to LDS cols o*32..o*32+31
        u16* dst = &As[g * STRIDE + o * 32];
        #pragma unroll
        for (int j = 0; j < 4; ++j) {
            unsigned w0 = pack2(a[j * 8 + 0] * inv, a[j * 8 + 1] * inv);
            unsigned w1 = pack2(a[j * 8 + 2] * inv, a[j * 8 + 3] * inv);
            unsigned w2 = pack2(a[j * 8 + 4] * inv, a[j * 8 + 5] * inv);
            unsigned w3 = pack2(a[j * 8 + 6] * inv, a[j * 8 + 7] * inv);
            uint4 pk4 = make_uint4(w0, w1, w2, w3);
            *(uint4*)(dst + j * 8) = pk4;
        }
    }

    // ---- prefetch ALL B fragments (L2-hot; overlap barrier wait) ----
    short8 bq[NK][2];
    {
        const u16* wr0 = WT + (size_t)(w * 32 + r) * K + q * 8;
        const u16* wr1 = WT + (size_t)(w * 32 + 16 + r) * K + q * 8;
        #pragma unroll
        for (int kk = 0; kk < NK; ++kk) {
            bq[kk][0] = *(const short8*)(wr0 + kk * 32);
            bq[kk][1] = *(const short8*)(wr1 + kk * 32);
        }
    }
    __syncthreads();

    floatx4 acc[4][2];
    #pragma unroll
    for (int mi = 0; mi < 4; ++mi)
        #pragma unroll
        for (int ni = 0; ni < 2; ++ni)
            acc[mi][ni] = (floatx4){0.f, 0.f, 0.f, 0.f};

    #pragma unroll
    for (int kk = 0; kk < NK; ++kk) {
        short8 af[4];
        #pragma unroll
        for (int mi = 0; mi < 4; ++mi)
            af[mi] = *(const short8*)(&As[(mi * 16 + r) * STRIDE + kk * 32 + q * 8]);
        #pragma unroll
        for (int mi = 0; mi < 4; ++mi) {
            acc[mi][0] = __builtin_amdgcn_mfma_f32_16x16x32_bf16(af[mi], bq[kk][0], acc[mi][0], 0, 0, 0);
            acc[mi][1] = __builtin_amdgcn_mfma_f32_16x16x32_bf16(af[mi], bq[kk][1], acc[mi][1], 0, 0, 0);
        }
    }

    #pragma unroll
    for (int mi = 0; mi < 4; ++mi)
        #pragma unroll
        for (int ni = 0; ni < 2; ++ni) {
            int colv = w * 32 + ni * 16 + r;
            float al = alpha[colv], be = beta[colv];
            #pragma unroll
            for (int r4 = 0; r4 < 4; ++r4) {
                int lrow = mi * 16 + q * 4 + r4;
                int row = mBase + lrow;
                if (row < M) {
                    float v = acc[mi][ni][r4] * al + be;
                    if (relu) v = fmaxf(v, 0.0f);
                    if (addRes) v += b2f(As[lrow * STRIDE + 128 + colv]);
                    if (outB) {
                        if (colv < 64) out8[(size_t)row * 64 + colv] = f2e4m3(v);
                        else outB[(size_t)row * 64 + (colv - 64)] = f2b(v);
                    } else {
                        out[(size_t)row * ldo + colv] = f2b(v);
                        if (out8) out8[(size_t)row * ld8 + colv] = f2e4m3(v);
                    }
                }
            }
        }
}

// ---------------- plain SAGE GEMM (layer 3, K=128, no aggregation) ----------------
template <int K>
__global__ __launch_bounds__(256) void gemm_sage_kernel(
    const u16* __restrict__ A1, const u16* __restrict__ A2,
    const u16* __restrict__ WT,
    const float* __restrict__ alpha, const float* __restrict__ beta,
    int addRes, u16* __restrict__ out, int ldo, u16* __restrict__ outB,
    u8* __restrict__ out8, int ld8,
    int M, int relu) {
    extern __shared__ u16 As[];          // 64 x (K+8)
    constexpr int STRIDE = K + 8;
    constexpr int NK = K / 32;
    int tid = threadIdx.x;
    int mBase = blockIdx.x * 64;
    int lane = tid & 63, w = tid >> 6;
    int q = lane >> 4, r = lane & 15;

    short8 bq[NK][2];
    {
        const u16* wr0 = WT + (size_t)(w * 32 + r) * K + q * 8;
        const u16* wr1 = WT + (size_t)(w * 32 + 16 + r) * K + q * 8;
        #pragma unroll
        for (int kk = 0; kk < NK; ++kk) {
            bq[kk][0] = *(const short8*)(wr0 + kk * 32);
            bq[kk][1] = *(const short8*)(wr1 + kk * 32);
        }
    }

    {
        int row = tid >> 2, cb = (tid & 3) * 8;
        int gr = mBase + row;
        #pragma unroll
        for (int j = 0; j < K; j += 32) {
            int k = cb + j;
            short8 v = (short8){0, 0, 0, 0, 0, 0, 0, 0};
            if (gr < M) {
                const u16* src = (k < 128) ? (A1 + (size_t)gr * 128 + k)
                                           : (A2 + (size_t)gr * 128 + (k - 128));
                v = *(const short8*)src;
            }
            *(short8*)(&As[row * STRIDE + k]) = v;
        }
    }
    __syncthreads();

    floatx4 acc[4][2];
    #pragma unroll
    for (int mi = 0; mi < 4; ++mi)
        #pragma unroll
        for (int ni = 0; ni < 2; ++ni)
            acc[mi][ni] = (floatx4){0.f, 0.f, 0.f, 0.f};

    #pragma unroll
    for (int kk = 0; kk < NK; ++kk) {
        short8 af[4];
        #pragma unroll
        for (int mi = 0; mi < 4; ++mi)
            af[mi] = *(const short8*)(&As[(mi * 16 + r) * STRIDE + kk * 32 + q * 8]);
        #pragma unroll
        for (int mi = 0; mi < 4; ++mi) {
            acc[mi][0] = __builtin_amdgcn_mfma_f32_16x16x32_bf16(af[mi], bq[kk][0], acc[mi][0], 0, 0, 0);
            acc[mi][1] = __builtin_amdgcn_mfma_f32_16x16x32_bf16(af[mi], bq[kk][1], acc[mi][1], 0, 0, 0);
        }
    }

    #pragma unroll
    for (int mi = 0; mi < 4; ++mi)
        #pragma unroll
        for (int ni = 0; ni < 2; ++ni) {
            int colv = w * 32 + ni * 16 + r;
            float al = alpha[colv], be = beta[colv];
            #pragma unroll
            for (int r4 = 0; r4 < 4; ++r4) {
                int lrow = mi * 16 + q * 4 + r4;
                int row = mBase + lrow;
                if (row < M) {
                    float v = acc[mi][ni][r4] * al + be;
                    if (relu) v = fmaxf(v, 0.0f);
                    if (K > 128 && addRes) v += b2f(As[lrow * STRIDE + 128 + colv]);
                    if (outB) {
                        if (colv < 64) out8[(size_t)row * 64 + colv] = f2e4m3(v);
                        else outB[(size_t)row * 64 + (colv - 64)] = f2b(v);
                    } else {
                        out[(size_t)row * ldo + colv] = f2b(v);
                        if (out8) out8[(size_t)row * ld8 + colv] = f2e4m3(v);
                    }
                }
            }
        }
}

// ---------------- fused edge decoder (64 edges/block, pos+neg merged, wn-split) ----------------
__global__ __launch_bounds__(256) void decode_kernel(
    const u16* __restrict__ z,
    const int* __restrict__ pos, const int* __restrict__ neg,
    int nPos, int nNeg, int blocksPos,
    const u16* __restrict__ WebT,
    const float* __restrict__ dparams,
    void* __restrict__ dout, long long posBase,
    const int* __restrict__ flags) {
    __shared__ u16 As[64 * 136];
    __shared__ float red[4][64];
    __shared__ float be1f[128], We2f[128];
    int tid = threadIdx.x;
    int f = flags[0];
    int b = blockIdx.x;
    const int* sidx; const int* didx; int nE; long long outBase; int eBase;
    if (b < blocksPos) {
        sidx = pos; didx = pos + nPos; nE = nPos; outBase = posBase; eBase = b * 64;
    } else {
        sidx = neg; didx = neg + nNeg; nE = nNeg; outBase = posBase + nPos;
        eBase = (b - blocksPos) * 64;
    }

    int lane = tid & 63, w = tid >> 6;
    int q = lane >> 4, r = lane & 15;

    short8 zr[4];
    {
        int row = tid >> 2, ch = tid & 3;
        int e = eBase + row;
        if (e >= nE) e = nE - 1;
        int node = (ch < 2) ? sidx[e] : didx[e];
        int off = (ch & 1) * 32;
        const short8* src = (const short8*)(z + (size_t)node * 64 + off);
        #pragma unroll
        for (int j = 0; j < 4; ++j) zr[j] = src[j];
    }

    if (tid < 128) { be1f[tid] = dparams[tid]; We2f[tid] = dparams[128 + tid]; }

    short8 bfw[4][2];   // [k0/32][ni]
    {
        const u16* w0 = WebT + (size_t)(w * 32 + r) * 128 + q * 8;
        const u16* w1 = WebT + (size_t)(w * 32 + 16 + r) * 128 + q * 8;
        #pragma unroll
        for (int kk = 0; kk < 4; ++kk) {
            bfw[kk][0] = *(const short8*)(w0 + kk * 32);
            bfw[kk][1] = *(const short8*)(w1 + kk * 32);
        }
    }

    {
        int row = tid >> 2, ch = tid & 3;
        #pragma unroll
        for (int j = 0; j < 4; ++j)
            *(short8*)(&As[row * 136 + ch * 32 + j * 8]) = zr[j];
    }
    __syncthreads();

    floatx4 acc[4][2];
    #pragma unroll
    for (int mi = 0; mi < 4; ++mi)
        #pragma unroll
        for (int ni = 0; ni < 2; ++ni)
            acc[mi][ni] = (floatx4){0.f, 0.f, 0.f, 0.f};

    #pragma unroll
    for (int kk = 0; kk < 4; ++kk) {
        short8 af[4];
        #pragma unroll
        for (int mi = 0; mi < 4; ++mi)
            af[mi] = *(const short8*)(&As[(mi * 16 + r) * 136 + kk * 32 + q * 8]);
        #pragma unroll
        for (int mi = 0; mi < 4; ++mi) {
            acc[mi][0] = __builtin_amdgcn_mfma_f32_16x16x32_bf16(af[mi], bfw[kk][0], acc[mi][0], 0, 0, 0);
            acc[mi][1] = __builtin_amdgcn_mfma_f32_16x16x32_bf16(af[mi], bfw[kk][1], acc[mi][1], 0, 0, 0);
        }
    }

    float part[4][4];
    #pragma unroll
    for (int mi = 0; mi < 4; ++mi)
        #pragma unroll
        for (int r4 = 0; r4 < 4; ++r4) part[mi][r4] = 0.f;
    #pragma unroll
    for (int mi = 0; mi < 4; ++mi)
        #pragma unroll
        for (int ni = 0; ni < 2; ++ni) {
            int colv = w * 32 + ni * 16 + r;
            float bb = be1f[colv], mm = We2f[colv];
            #pragma unroll
            for (int r4 = 0; r4 < 4; ++r4) {
                float v = acc[mi][ni][r4] + bb;
                part[mi][r4] += fmaxf(v, 0.0f) * mm;
            }
        }
    #pragma unroll
    for (int mi = 0; mi < 4; ++mi)
        #pragma unroll
        for (int r4 = 0; r4 < 4; ++r4) {
            float v = part[mi][r4];
            v += __shfl_xor(v, 1, 64);
            v += __shfl_xor(v, 2, 64);
            v += __shfl_xor(v, 4, 64);
            v += __shfl_xor(v, 8, 64);
            part[mi][r4] = v;
        }
    if (r == 0) {
        #pragma unroll
        for (int mi = 0; mi < 4; ++mi)
            #pragma unroll
            for (int r4 = 0; r4 < 4; ++r4)
                red[w][mi * 16 + q * 4 + r4] = part[mi][r4];
    }
    __syncthreads();
    if (tid < 64) {
        int e = eBase + tid;
        if (e < nE) {
            float s = red[0][tid] + red[1][tid] + red[2][tid] + red[3][tid] + dparams[256];
            float sg = 1.0f / (1.0f + expf(-s));
            if (f) ((float*)dout)[outBase + e] = sg;
            else   ((u16*)dout)[outBase + e] = f2b(sg);
        }
    }
}

// ---------------- launch ----------------

extern "C" void kernel_launch(void* const* d_in, const int* in_sizes, int n_in,
                              void* d_out, int out_size, void* d_ws, size_t ws_size,
                              hipStream_t stream) {
    const void* x   = d_in[0];
    const int* ei   = (const int*)d_in[1];
    const int* pos  = (const int*)d_in[2];
    const int* neg  = (const int*)d_in[3];
    const void* Wl1 = d_in[4];
    const void* bl1 = d_in[5];
    const void* Wr1 = d_in[6];
    const void* g1  = d_in[7];
    const void* b1  = d_in[8];
    const void* Wl2 = d_in[9];
    const void* bl2 = d_in[10];
    const void* Wr2 = d_in[11];
    const void* g2  = d_in[12];
    const void* b2  = d_in[13];
    const void* Wl3 = d_in[14];
    const void* bl3 = d_in[15];
    const void* Wr3 = d_in[16];
    const void* We1 = d_in[17];
    const void* be1 = d_in[18];
    const void* We2 = d_in[19];
    const void* be2 = d_in[20];

    const int N = in_sizes[0] / 128;
    const int E = in_sizes[1] / 2;
    const int nPos = in_sizes[2] / 2;
    const int nNeg = in_sizes[3] / 2;
    const int nbuck = (N + 127) >> 7;
    const int nbuckP = (nbuck + 15) & ~15;     // pad rows to 64B
    const int EPB = 4096;                      // high-TLP CSR build grid
    const int B1 = (E + EPB - 1) / EPB;

    char* p = (char*)d_ws;
    auto alloc = [&](size_t bytes) -> void* {
        void* r = (void*)p;
        p += (bytes + 255) & ~(size_t)255;
        return r;
    };
    int*   flags     = (int*)alloc(64);
    int*   blockhist = (int*)alloc((size_t)B1 * nbuckP * 4);
    int*   coltot    = (int*)alloc((size_t)nbuck * 4);
    int*   bucketbase= (int*)alloc((size_t)nbuck * 4);
    int*   rowptr    = (int*)alloc((size_t)(N + 1) * 4);
    unsigned* pairs  = (unsigned*)alloc((size_t)E * 4);
    int*   colbuf    = (int*)alloc((size_t)E * 4);
    u16*   xb      = (u16*)alloc((size_t)N * 128 * 2);   // reused as hbufB
    u16*   hbufA   = (u16*)alloc((size_t)N * 128 * 2);   // reused as zbuf
    u16*   meanbuf = (u16*)alloc((size_t)N * 128 * 2);   // ubuf lives here
    u8*    x8      = (u8*)alloc((size_t)N * 128);
    u8*    h8      = (u8*)alloc((size_t)N * 128);
    u8*    t8      = (u8*)alloc((size_t)N * 64);
    u16*   Wcat1   = (u16*)alloc((size_t)256 * 128 * 2);
    u16*   Wcat2   = (u16*)alloc((size_t)256 * 128 * 2);
    u16*   Wcat3   = (u16*)alloc((size_t)128 * 128 * 2);
    u16*   Web     = (u16*)alloc((size_t)128 * 128 * 2);
    float* al1 = (float*)alloc(128 * 4);
    float* bt1 = (float*)alloc(128 * 4);
    float* al2 = (float*)alloc(128 * 4);
    float* bt2 = (float*)alloc(128 * 4);
    float* al3 = (float*)alloc(128 * 4);
    float* bt3 = (float*)alloc(128 * 4);
    float* dparams = (float*)alloc(260 * 4);
    u16* hbufB = xb;
    u16* ubuf  = meanbuf + (size_t)N * 64;
    u16* zbuf  = hbufA + (size_t)N * 64;     // hbufA free after gemm2

    // dtype sniff + bucketed CSR build (no global atomics)
    sniff_kernel<<<1, 256, 0, stream>>>((const unsigned*)x, ei, flags);
    bucket_count_kernel<<<B1, 256, 0, stream>>>(ei, blockhist, E, EPB, nbuckP, nbuck, flags);
    colscan_kernel<<<nbuck, 64, 0, stream>>>(blockhist, coltot, B1, nbuckP);
    base_scan_kernel<<<1, 1024, 0, stream>>>(coltot, bucketbase, rowptr + N, nbuck, E);
    bucket_scatter_kernel<<<B1, 256, 0, stream>>>(ei, bucketbase, blockhist, pairs, E, EPB, nbuckP, nbuck, flags);
    bucket_csr_kernel<<<nbuck, 256, 0, stream>>>(pairs, bucketbase, coltot, rowptr, colbuf, N);

    // input / parameter conversion
    cvt_x_kernel<<<(N * 64 + 255) / 256, 256, 0, stream>>>(x, xb, (u16*)x8, flags, N * 64);
    prep_all_kernel<<<(66048 + 255) / 256, 256, 0, stream>>>(
        Wl1, Wr1, Wcat1, Wl2, Wr2, Wcat2, Wl3, Wr3, Wcat3, We1, Web,
        g1, b1, bl1, al1, bt1, g2, b2, bl2, al2, bt2, bl3, al3, bt3,
        be1, We2, be2, dparams, flags);

    int gB = (N + 63) / 64;
    size_t lds256 = (size_t)64 * (256 + 8) * 2;
    size_t lds128 = (size_t)64 * (128 + 8) * 2;

    // layer 1 (fused agg+gemm): h1 = relu(bn([mean(x8)|x]@W1)) + x -> hbufA + h8
    fused_agg_gemm_kernel<<<gB, 256, lds256, stream>>>(x8, rowptr, colbuf, xb, Wcat1,
                                                       al1, bt1, 1, hbufA, 128, nullptr,
                                                       h8, 128, N, 1);
    // layer 2 (fused agg+gemm): h2 -> hbufB (bf16 only)
    fused_agg_gemm_kernel<<<gB, 256, lds256, stream>>>(h8, rowptr, colbuf, hbufA, Wcat2,
                                                       al2, bt2, 1, hbufB, 128, nullptr,
                                                       nullptr, 0, N, 1);
    // layer 3 (commuted): [t|u] = h2@[Wl3|Wr3]; t -> t8 (fp8), u -> ubuf (bf16)
    gemm_sage_kernel<128><<<gB, 256, lds128, stream>>>(hbufB, hbufB, Wcat3, al3, bt3,
                                                       0, nullptr, 0, ubuf, t8, 64, N, 0);
    // z = mean(t8) + u -> zbuf + d_out
    agg_combine_kernel<<<(N + 63) / 64, 256, 0, stream>>>(t8, rowptr, colbuf, ubuf, zbuf,
                                                          d_out, N, flags);

    // decode pos + neg in one launch (64 edges/block)
    long long posBase = (long long)N * 64;
    int bP = (nPos + 63) / 64, bN = (nNeg + 63) / 64;
    decode_kernel<<<bP + bN, 256, 0, stream>>>(zbuf, pos, neg, nPos, nNeg, bP,
                                               Web, dparams, d_out, posBase, flags);
}

// Round 17
// 445.351 us; speedup vs baseline: 1.0335x; 1.0335x over previous
//
#include <hip/hip_runtime.h>
#include <hip/hip_bf16.h>

typedef unsigned short u16;
typedef unsigned char u8;
typedef short short8 __attribute__((ext_vector_type(8)));
typedef float floatx4 __attribute__((ext_vector_type(4)));
typedef float floatx2 __attribute__((ext_vector_type(2)));

__device__ __forceinline__ float b2f(u16 u) {
    unsigned v = ((unsigned)u) << 16;
    float f;
    __builtin_memcpy(&f, &v, 4);
    return f;
}
__device__ __forceinline__ float b2f_lo(unsigned w) { return b2f((u16)(w & 0xffffu)); }
__device__ __forceinline__ float b2f_hi(unsigned w) { return b2f((u16)(w >> 16)); }
__device__ __forceinline__ u16 f2b(float f) {
    unsigned u;
    __builtin_memcpy(&u, &f, 4);
    u = u + 0x7fffu + ((u >> 16) & 1u);
    return (u16)(u >> 16);
}
__device__ __forceinline__ unsigned pack2(float a, float b) {
    return (unsigned)f2b(a) | ((unsigned)f2b(b) << 16);
}
__device__ __forceinline__ float loadp(const void* p, int i, int f) {
    return f ? ((const float*)p)[i] : b2f(((const u16*)p)[i]);
}
__device__ __forceinline__ u8 f2e4m3(float v) {
    int r = __builtin_amdgcn_cvt_pk_fp8_f32(v, v, 0, false);
    return (u8)(r & 0xff);
}
// accumulate 16 fp8 values (one uint4) into a[16]
__device__ __forceinline__ void acc16_fp8(float* a, uint4 p) {
    floatx2 f;
    f = __builtin_amdgcn_cvt_pk_f32_fp8((int)p.x, false); a[0] += f[0];  a[1] += f[1];
    f = __builtin_amdgcn_cvt_pk_f32_fp8((int)p.x, true);  a[2] += f[0];  a[3] += f[1];
    f = __builtin_amdgcn_cvt_pk_f32_fp8((int)p.y, false); a[4] += f[0];  a[5] += f[1];
    f = __builtin_amdgcn_cvt_pk_f32_fp8((int)p.y, true);  a[6] += f[0];  a[7] += f[1];
    f = __builtin_amdgcn_cvt_pk_f32_fp8((int)p.z, false); a[8] += f[0];  a[9] += f[1];
    f = __builtin_amdgcn_cvt_pk_f32_fp8((int)p.z, true);  a[10] += f[0]; a[11] += f[1];
    f = __builtin_amdgcn_cvt_pk_f32_fp8((int)p.w, false); a[12] += f[0]; a[13] += f[1];
    f = __builtin_amdgcn_cvt_pk_f32_fp8((int)p.w, true);  a[14] += f[0]; a[15] += f[1];
}

// ---------------- dtype sniffing ----------------
__global__ void sniff_kernel(const unsigned* __restrict__ xw, const int* __restrict__ eiw,
                             int* __restrict__ flags) {
    __shared__ int s_fp32, s_i64;
    if (threadIdx.x == 0) { s_fp32 = 0; s_i64 = 1; }
    __syncthreads();
    int t = threadIdx.x;  // 256 threads
    unsigned w = xw[t];
    float lo = b2f_lo(w);
    if (!(fabsf(lo) <= 64.0f)) atomicOr(&s_fp32, 1);   // also catches NaN
    if (eiw[2 * t + 1] != 0) atomicAnd(&s_i64, 0);
    __syncthreads();
    if (t == 0) { flags[0] = s_fp32; flags[1] = s_i64; }
}

// ---------------- input conversion (bf16 + fp8 shadow) ----------------
__global__ void cvt_x_kernel(const void* __restrict__ x, u16* __restrict__ xb,
                             u16* __restrict__ x8,   // fp8 pairs stored as u16
                             const int* __restrict__ flags, int nPairs) {
    int f = flags[0];
    int i = blockIdx.x * 256 + threadIdx.x;
    if (i >= nPairs) return;
    float lo, hi;
    if (f) {
        float2 v = ((const float2*)x)[i];
        lo = v.x; hi = v.y;
        ((unsigned*)xb)[i] = pack2(lo, hi);
    } else {
        unsigned w = ((const unsigned*)x)[i];
        lo = b2f_lo(w); hi = b2f_hi(w);
        ((unsigned*)xb)[i] = w;
    }
    int r = __builtin_amdgcn_cvt_pk_fp8_f32(lo, hi, 0, false);
    x8[i] = (u16)(r & 0xffff);
}

// ---------------- fused parameter prep (one launch) ----------------
__global__ void prep_all_kernel(const void* Wl1, const void* Wr1, u16* __restrict__ Wcat1,
                                const void* Wl2, const void* Wr2, u16* __restrict__ Wcat2,
                                const void* Wl3, const void* Wr3, u16* __restrict__ Wcat3,
                                const void* We1, u16* __restrict__ Web,
                                const void* g1, const void* b1, const void* bl1,
                                float* __restrict__ al1, float* __restrict__ bt1,
                                const void* g2, const void* b2, const void* bl2,
                                float* __restrict__ al2, float* __restrict__ bt2,
                                const void* bl3,
                                float* __restrict__ al3, float* __restrict__ bt3,
                                const void* be1, const void* We2, const void* be2,
                                float* __restrict__ dparams,
                                const int* __restrict__ flags) {
    int f = flags[0];
    int idx = blockIdx.x * 256 + threadIdx.x;
    if (idx < 16384) {
        int k = idx >> 7, n = idx & 127;           // Wl1/Wr1: [k=128][n=128]
        Wcat1[n * 256 + k]       = f ? f2b(((const float*)Wl1)[idx]) : ((const u16*)Wl1)[idx];
        Wcat1[n * 256 + 128 + k] = f ? f2b(((const float*)Wr1)[idx]) : ((const u16*)Wr1)[idx];
    } else if (idx < 32768) {
        int i = idx - 16384;
        int k = i >> 7, n = i & 127;
        Wcat2[n * 256 + k]       = f ? f2b(((const float*)Wl2)[i]) : ((const u16*)Wl2)[i];
        Wcat2[n * 256 + 128 + k] = f ? f2b(((const float*)Wr2)[i]) : ((const u16*)Wr2)[i];
    } else if (idx < 49152) {
        int i = idx - 32768;
        int k = i >> 7, n = i & 127;               // combined [k=128][n=128], n<64 Wl3 else Wr3
        const void* src = (n < 64) ? Wl3 : Wr3;
        int j = k * 64 + (n & 63);
        Wcat3[n * 128 + k] = f ? f2b(((const float*)src)[j]) : ((const u16*)src)[j];
    } else if (idx < 65536) {
        int i = idx - 49152;
        int k = i >> 7, n = i & 127;               // We1: [k=128][n=128]
        Web[n * 128 + k] = f ? f2b(((const float*)We1)[i]) : ((const u16*)We1)[i];
    } else {
        int i = idx - 65536;
        if (i < 128) {
            float s = loadp(g1, i, f) * rsqrtf(1.0f + 1e-5f);
            al1[i] = s;
            bt1[i] = loadp(bl1, i, f) * s + loadp(b1, i, f);
        } else if (i < 256) {
            int j = i - 128;
            float s = loadp(g2, j, f) * rsqrtf(1.0f + 1e-5f);
            al2[j] = s;
            bt2[j] = loadp(bl2, j, f) * s + loadp(b2, j, f);
        } else if (i < 384) {
            int j = i - 256;
            al3[j] = 1.0f;
            bt3[j] = (j < 64) ? 0.0f : loadp(bl3, j - 64, f);
        } else if (i < 512) {
            int j = i - 384;
            dparams[j] = loadp(be1, j, f);
            dparams[128 + j] = loadp(We2, j, f);
            if (j == 0) dparams[256] = loadp(be2, 0, f);
        }
    }
}

// ---------------- CSR build: two-level counting sort (no global atomics) ----------------
// blockhist layout [b][nbuckP]: count-write and scatter-read are COALESCED.
// pairs packed to 4B: src | (d&127)<<25  (valid for N < 2^25).
__device__ __forceinline__ int edge_at(const int* ei, long long idx, int i64) {
    return i64 ? ei[2 * idx] : ei[idx];
}

__global__ __launch_bounds__(256) void bucket_count_kernel(const int* __restrict__ ei,
                                                           int* __restrict__ blockhist,
                                                           int E, int EPB, int nbuckP, int nbuck,
                                                           const int* __restrict__ flags) {
    __shared__ int hist[1024];
    for (int i = threadIdx.x; i < nbuck; i += 256) hist[i] = 0;
    __syncthreads();
    int i64 = flags[1];
    int b = blockIdx.x;
    int lo = b * EPB, hi = min(lo + EPB, E);
    for (int e = lo + (int)threadIdx.x; e < hi; e += 256) {
        int d = edge_at(ei, (long long)E + e, i64);
        atomicAdd(&hist[d >> 7], 1);
    }
    __syncthreads();
    for (int k = threadIdx.x; k < nbuck; k += 256)
        blockhist[(size_t)b * nbuckP + k] = hist[k];
}

// looped 64-wide exclusive scan (over blocks b) with carry; strided reads, high TLP
__global__ __launch_bounds__(64) void colscan_kernel(int* __restrict__ blockhist,
                                                     int* __restrict__ coltot,
                                                     int B1, int nbuckP) {
    int k = blockIdx.x, l = threadIdx.x;
    int carry = 0;
    for (int base = 0; base < B1; base += 64) {
        int idx = base + l;
        int x = (idx < B1) ? blockhist[(size_t)idx * nbuckP + k] : 0;
        int s = x;
        #pragma unroll
        for (int off = 1; off < 64; off <<= 1) {
            int u = __shfl_up(s, off, 64);
            if (l >= off) s += u;
        }
        if (idx < B1) blockhist[(size_t)idx * nbuckP + k] = carry + s - x;
        carry += __shfl(s, 63, 64);
    }
    if (l == 0) coltot[k] = carry;
}

__global__ __launch_bounds__(1024) void base_scan_kernel(const int* __restrict__ coltot,
                                                         int* __restrict__ bucketbase,
                                                         int* __restrict__ rowptrN,
                                                         int nbuck, int E) {
    __shared__ int wsum[16];
    int t = threadIdx.x, lane = t & 63, w = t >> 6;
    int v = (t < nbuck) ? coltot[t] : 0;
    int inc = v;
    #pragma unroll
    for (int off = 1; off < 64; off <<= 1) {
        int u = __shfl_up(inc, off, 64);
        if (lane >= off) inc += u;
    }
    if (lane == 63) wsum[w] = inc;
    __syncthreads();
    int add = 0;
    for (int i = 0; i < w; ++i) add += wsum[i];
    if (t < nbuck) bucketbase[t] = add + inc - v;
    if (t == 0) rowptrN[0] = E;
}

__global__ __launch_bounds__(256) void bucket_scatter_kernel(const int* __restrict__ ei,
                                                             const int* __restrict__ bucketbase,
                                                             const int* __restrict__ blockhist,
                                                             unsigned* __restrict__ pairs,
                                                             int E, int EPB, int nbuckP, int nbuck,
                                                             const int* __restrict__ flags) {
    __shared__ int off[1024];
    int b = blockIdx.x;
    for (int k = threadIdx.x; k < nbuck; k += 256)
        off[k] = bucketbase[k] + blockhist[(size_t)b * nbuckP + k];
    __syncthreads();
    int i64 = flags[1];
    int lo = b * EPB, hi = min(lo + EPB, E);
    for (int e = lo + (int)threadIdx.x; e < hi; e += 256) {
        int s = edge_at(ei, e, i64);
        int d = edge_at(ei, (long long)E + e, i64);
        int slot = atomicAdd(&off[d >> 7], 1);
        pairs[slot] = (unsigned)s | ((unsigned)(d & 127) << 25);
    }
}

__global__ __launch_bounds__(256) void bucket_csr_kernel(const unsigned* __restrict__ pairs,
                                                         const int* __restrict__ bucketbase,
                                                         const int* __restrict__ coltot,
                                                         int* __restrict__ rowptr,
                                                         int* __restrict__ col, int N) {
    __shared__ unsigned pk[4096];
    __shared__ int hist[128], cur[128];
    int k = blockIdx.x, tid = threadIdx.x;
    if (tid < 128) hist[tid] = 0;
    __syncthreads();
    int base = bucketbase[k], cnt = coltot[k];
    int staged = min(cnt, 4096);
    for (int i = tid; i < cnt; i += 256) {
        unsigned pv = pairs[base + i];
        int j = (int)(pv >> 25);
        atomicAdd(&hist[j], 1);
        if (i < 4096) pk[i] = pv;
    }
    __syncthreads();
    if (tid < 64) {
        int x0 = hist[tid], x1 = hist[64 + tid];
        int s0 = x0;
        #pragma unroll
        for (int off = 1; off < 64; off <<= 1) {
            int u = __shfl_up(s0, off, 64);
            if (tid >= off) s0 += u;
        }
        int tot0 = __shfl(s0, 63, 64);
        int s1 = x1;
        #pragma unroll
        for (int off = 1; off < 64; off <<= 1) {
            int u = __shfl_up(s1, off, 64);
            if (tid >= off) s1 += u;
        }
        s1 += tot0;
        cur[tid] = s0 - x0;
        cur[64 + tid] = s1 - x1;
    }
    __syncthreads();
    int node0 = k << 7;
    if (tid < 128 && node0 + tid < N) rowptr[node0 + tid] = base + cur[tid];
    __syncthreads();
    for (int i = tid; i < staged; i += 256) {
        unsigned pv = pk[i];
        int slot = base + atomicAdd(&cur[pv >> 25], 1);
        col[slot] = (int)(pv & 0x1FFFFFFu);
    }
    for (int i = 4096 + tid; i < cnt; i += 256) {
        unsigned pv = pairs[base + i];
        int slot = base + atomicAdd(&cur[pv >> 25], 1);
        col[slot] = (int)(pv & 0x1FFFFFFu);
    }
}

// ---------------- mean aggregation over fp8 rows -> bf16 means ----------------
// 8-deep independent gather unroll for memory-level parallelism (latency-bound regime).
template <int CH>
__global__ __launch_bounds__(256) void aggregate_fp8_kernel(const u8* __restrict__ X8,
                                                            const int* __restrict__ rowptr,
                                                            const int* __restrict__ col,
                                                            u16* __restrict__ meanout, int N) {
    constexpr int LPR = CH / 16;
    constexpr int GPB = 256 / LPR;
    int t = threadIdx.x;
    int g = t / LPR;
    int o = t % LPR;
    int u = blockIdx.x * GPB + g;
    if (u >= N) return;
    const uint4* Xv = (const uint4*)X8;
    int beg = rowptr[u], end = rowptr[u + 1];
    float a[16];
    #pragma unroll
    for (int i = 0; i < 16; ++i) a[i] = 0.f;
    int e = beg;
    for (; e + 8 <= end; e += 8) {
        uint4 p0 = Xv[(size_t)col[e]     * LPR + o];
        uint4 p1 = Xv[(size_t)col[e + 1] * LPR + o];
        uint4 p2 = Xv[(size_t)col[e + 2] * LPR + o];
        uint4 p3 = Xv[(size_t)col[e + 3] * LPR + o];
        uint4 p4 = Xv[(size_t)col[e + 4] * LPR + o];
        uint4 p5 = Xv[(size_t)col[e + 5] * LPR + o];
        uint4 p6 = Xv[(size_t)col[e + 6] * LPR + o];
        uint4 p7 = Xv[(size_t)col[e + 7] * LPR + o];
        acc16_fp8(a, p0); acc16_fp8(a, p1); acc16_fp8(a, p2); acc16_fp8(a, p3);
        acc16_fp8(a, p4); acc16_fp8(a, p5); acc16_fp8(a, p6); acc16_fp8(a, p7);
    }
    for (; e + 4 <= end; e += 4) {
        uint4 p0 = Xv[(size_t)col[e]     * LPR + o];
        uint4 p1 = Xv[(size_t)col[e + 1] * LPR + o];
        uint4 p2 = Xv[(size_t)col[e + 2] * LPR + o];
        uint4 p3 = Xv[(size_t)col[e + 3] * LPR + o];
        acc16_fp8(a, p0); acc16_fp8(a, p1); acc16_fp8(a, p2); acc16_fp8(a, p3);
    }
    for (; e < end; ++e) {
        uint4 p = Xv[(size_t)col[e] * LPR + o];
        acc16_fp8(a, p);
    }
    int deg = end - beg;
    float inv = (deg > 0) ? 1.0f / (float)deg : 0.0f;
    uint4 ov0, ov1;
    ov0.x = pack2(a[0] * inv, a[1] * inv);   ov0.y = pack2(a[2] * inv, a[3] * inv);
    ov0.z = pack2(a[4] * inv, a[5] * inv);   ov0.w = pack2(a[6] * inv, a[7] * inv);
    ov1.x = pack2(a[8] * inv, a[9] * inv);   ov1.y = pack2(a[10] * inv, a[11] * inv);
    ov1.z = pack2(a[12] * inv, a[13] * inv); ov1.w = pack2(a[14] * inv, a[15] * inv);
    uint4* mo = (uint4*)meanout;
    mo[(size_t)u * (CH / 8) + o * 2 + 0] = ov0;
    mo[(size_t)u * (CH / 8) + o * 2 + 1] = ov1;
}

// ---------------- fused layer-3 tail: z = mean_fp8(t8) + u ; write zbuf + d_out ----------------
__global__ __launch_bounds__(256) void agg_combine_kernel(const u8* __restrict__ T8,
                                                          const int* __restrict__ rowptr,
                                                          const int* __restrict__ col,
                                                          const u16* __restrict__ ubuf,
                                                          u16* __restrict__ zbuf,
                                                          void* __restrict__ dout,
                                                          int N, const int* __restrict__ flags) {
    constexpr int LPR = 4;           // 64 ch / 16
    constexpr int GPB = 64;
    int f = flags[0];
    int t = threadIdx.x;
    int g = t / LPR;
    int o = t % LPR;
    int u = blockIdx.x * GPB + g;
    if (u >= N) return;
    const uint4* Xv = (const uint4*)T8;
    int beg = rowptr[u], end = rowptr[u + 1];
    float a[16];
    #pragma unroll
    for (int i = 0; i < 16; ++i) a[i] = 0.f;
    int e = beg;
    for (; e + 8 <= end; e += 8) {
        uint4 p0 = Xv[(size_t)col[e]     * LPR + o];
        uint4 p1 = Xv[(size_t)col[e + 1] * LPR + o];
        uint4 p2 = Xv[(size_t)col[e + 2] * LPR + o];
        uint4 p3 = Xv[(size_t)col[e + 3] * LPR + o];
        uint4 p4 = Xv[(size_t)col[e + 4] * LPR + o];
        uint4 p5 = Xv[(size_t)col[e + 5] * LPR + o];
        uint4 p6 = Xv[(size_t)col[e + 6] * LPR + o];
        uint4 p7 = Xv[(size_t)col[e + 7] * LPR + o];
        acc16_fp8(a, p0); acc16_fp8(a, p1); acc16_fp8(a, p2); acc16_fp8(a, p3);
        acc16_fp8(a, p4); acc16_fp8(a, p5); acc16_fp8(a, p6); acc16_fp8(a, p7);
    }
    for (; e + 4 <= end; e += 4) {
        uint4 p0 = Xv[(size_t)col[e]     * LPR + o];
        uint4 p1 = Xv[(size_t)col[e + 1] * LPR + o];
        uint4 p2 = Xv[(size_t)col[e + 2] * LPR + o];
        uint4 p3 = Xv[(size_t)col[e + 3] * LPR + o];
        acc16_fp8(a, p0); acc16_fp8(a, p1); acc16_fp8(a, p2); acc16_fp8(a, p3);
    }
    for (; e < end; ++e) {
        uint4 p = Xv[(size_t)col[e] * LPR + o];
        acc16_fp8(a, p);
    }
    int deg = end - beg;
    float inv = (deg > 0) ? 1.0f / (float)deg : 0.0f;
    const uint4* uv = (const uint4*)(ubuf + (size_t)u * 64 + o * 16);
    uint4 u0 = uv[0], u1 = uv[1];
    float z[16];
    z[0] = a[0] * inv + b2f_lo(u0.x);  z[1] = a[1] * inv + b2f_hi(u0.x);
    z[2] = a[2] * inv + b2f_lo(u0.y);  z[3] = a[3] * inv + b2f_hi(u0.y);
    z[4] = a[4] * inv + b2f_lo(u0.z);  z[5] = a[5] * inv + b2f_hi(u0.z);
    z[6] = a[6] * inv + b2f_lo(u0.w);  z[7] = a[7] * inv + b2f_hi(u0.w);
    z[8] = a[8] * inv + b2f_lo(u1.x);  z[9] = a[9] * inv + b2f_hi(u1.x);
    z[10] = a[10] * inv + b2f_lo(u1.y); z[11] = a[11] * inv + b2f_hi(u1.y);
    z[12] = a[12] * inv + b2f_lo(u1.z); z[13] = a[13] * inv + b2f_hi(u1.z);
    z[14] = a[14] * inv + b2f_lo(u1.w); z[15] = a[15] * inv + b2f_hi(u1.w);
    uint4 zv0, zv1;
    zv0.x = pack2(z[0], z[1]);   zv0.y = pack2(z[2], z[3]);
    zv0.z = pack2(z[4], z[5]);   zv0.w = pack2(z[6], z[7]);
    zv1.x = pack2(z[8], z[9]);   zv1.y = pack2(z[10], z[11]);
    zv1.z = pack2(z[12], z[13]); zv1.w = pack2(z[14], z[15]);
    uint4* zo = (uint4*)(zbuf + (size_t)u * 64 + o * 16);
    zo[0] = zv0; zo[1] = zv1;
    if (f) {
        float* fo = (float*)dout + (size_t)u * 64 + o * 16;
        #pragma unroll
        for (int i = 0; i < 16; ++i) fo[i] = z[i];
    } else {
        uint4* bo = (uint4*)((u16*)dout + (size_t)u * 64 + o * 16);
        bo[0] = zv0; bo[1] = zv1;
    }
}

// ---------------- fused SAGE-layer GEMM (templated K, register-held B, single barrier) ----------------
template <int K>
__global__ __launch_bounds__(256) void gemm_sage_kernel(
    const u16* __restrict__ A1, const u16* __restrict__ A2,
    const u16* __restrict__ WT,
    const float* __restrict__ alpha, const float* __restrict__ beta,
    int addRes, u16* __restrict__ out, int ldo, u16* __restrict__ outB,
    u8* __restrict__ out8, int ld8,
    int M, int relu) {
    extern __shared__ u16 As[];          // 64 x (K+8)
    constexpr int STRIDE = K + 8;
    constexpr int NK = K / 32;
    int tid = threadIdx.x;
    int mBase = blockIdx.x * 64;
    int lane = tid & 63, w = tid >> 6;
    int q = lane >> 4, r = lane & 15;

    // ---- prefetch ALL B fragments into registers (L2-hot; overlaps A staging) ----
    short8 bq[NK][2];
    {
        const u16* wr0 = WT + (size_t)(w * 32 + r) * K + q * 8;
        const u16* wr1 = WT + (size_t)(w * 32 + 16 + r) * K + q * 8;
        #pragma unroll
        for (int kk = 0; kk < NK; ++kk) {
            bq[kk][0] = *(const short8*)(wr0 + kk * 32);
            bq[kk][1] = *(const short8*)(wr1 + kk * 32);
        }
    }

    // ---- stage full A tile (64 x K) ----
    {
        int row = tid >> 2, cb = (tid & 3) * 8;
        int gr = mBase + row;
        #pragma unroll
        for (int j = 0; j < K; j += 32) {
            int k = cb + j;
            short8 v = (short8){0, 0, 0, 0, 0, 0, 0, 0};
            if (gr < M) {
                const u16* src = (k < 128) ? (A1 + (size_t)gr * 128 + k)
                                           : (A2 + (size_t)gr * 128 + (k - 128));
                v = *(const short8*)src;
            }
            *(short8*)(&As[row * STRIDE + k]) = v;
        }
    }
    __syncthreads();

    floatx4 acc[4][2];
    #pragma unroll
    for (int mi = 0; mi < 4; ++mi)
        #pragma unroll
        for (int ni = 0; ni < 2; ++ni)
            acc[mi][ni] = (floatx4){0.f, 0.f, 0.f, 0.f};

    #pragma unroll
    for (int kk = 0; kk < NK; ++kk) {
        short8 af[4];
        #pragma unroll
        for (int mi = 0; mi < 4; ++mi)
            af[mi] = *(const short8*)(&As[(mi * 16 + r) * STRIDE + kk * 32 + q * 8]);
        #pragma unroll
        for (int mi = 0; mi < 4; ++mi) {
            acc[mi][0] = __builtin_amdgcn_mfma_f32_16x16x32_bf16(af[mi], bq[kk][0], acc[mi][0], 0, 0, 0);
            acc[mi][1] = __builtin_amdgcn_mfma_f32_16x16x32_bf16(af[mi], bq[kk][1], acc[mi][1], 0, 0, 0);
        }
    }

    #pragma unroll
    for (int mi = 0; mi < 4; ++mi)
        #pragma unroll
        for (int ni = 0; ni < 2; ++ni) {
            int colv = w * 32 + ni * 16 + r;
            float al = alpha[colv], be = beta[colv];
            #pragma unroll
            for (int r4 = 0; r4 < 4; ++r4) {
                int lrow = mi * 16 + q * 4 + r4;
                int row = mBase + lrow;
                if (row < M) {
                    float v = acc[mi][ni][r4] * al + be;
                    if (relu) v = fmaxf(v, 0.0f);
                    if (K > 128 && addRes) v += b2f(As[lrow * STRIDE + 128 + colv]);
                    if (outB) {
                        if (colv < 64) out8[(size_t)row * 64 + colv] = f2e4m3(v);
                        else outB[(size_t)row * 64 + (colv - 64)] = f2b(v);
                    } else {
                        out[(size_t)row * ldo + colv] = f2b(v);
                        if (out8) out8[(size_t)row * ld8 + colv] = f2e4m3(v);
                    }
                }
            }
        }
}

// ---------------- fused edge decoder (64 edges/block, pos+neg merged, wn-split) ----------------
__global__ __launch_bounds__(256) void decode_kernel(
    const u16* __restrict__ z,
    const int* __restrict__ pos, const int* __restrict__ neg,
    int nPos, int nNeg, int blocksPos,
    const u16* __restrict__ WebT,
    const float* __restrict__ dparams,
    void* __restrict__ dout, long long posBase,
    const int* __restrict__ flags) {
    __shared__ u16 As[64 * 136];
    __shared__ float red[4][64];
    __shared__ float be1f[128], We2f[128];
    int tid = threadIdx.x;
    int f = flags[0];
    int b = blockIdx.x;
    const int* sidx; const int* didx; int nE; long long outBase; int eBase;
    if (b < blocksPos) {
        sidx = pos; didx = pos + nPos; nE = nPos; outBase = posBase; eBase = b * 64;
    } else {
        sidx = neg; didx = neg + nNeg; nE = nNeg; outBase = posBase + nPos;
        eBase = (b - blocksPos) * 64;
    }

    int lane = tid & 63, w = tid >> 6;
    int q = lane >> 4, r = lane & 15;

    // ---- issue z-gather first (latency overlapped with weight loads below) ----
    short8 zr[4];
    {
        int row = tid >> 2, ch = tid & 3;
        int e = eBase + row;
        if (e >= nE) e = nE - 1;
        int node = (ch < 2) ? sidx[e] : didx[e];
        int off = (ch & 1) * 32;
        const short8* src = (const short8*)(z + (size_t)node * 64 + off);
        #pragma unroll
        for (int j = 0; j < 4; ++j) zr[j] = src[j];
    }

    if (tid < 128) { be1f[tid] = dparams[tid]; We2f[tid] = dparams[128 + tid]; }

    // ---- B-fragments: held in registers, WebT read exactly once per block ----
    short8 bfw[4][2];   // [k0/32][ni]
    {
        const u16* w0 = WebT + (size_t)(w * 32 + r) * 128 + q * 8;
        const u16* w1 = WebT + (size_t)(w * 32 + 16 + r) * 128 + q * 8;
        #pragma unroll
        for (int kk = 0; kk < 4; ++kk) {
            bfw[kk][0] = *(const short8*)(w0 + kk * 32);
            bfw[kk][1] = *(const short8*)(w1 + kk * 32);
        }
    }

    // ---- write staged z rows to LDS ----
    {
        int row = tid >> 2, ch = tid & 3;
        #pragma unroll
        for (int j = 0; j < 4; ++j)
            *(short8*)(&As[row * 136 + ch * 32 + j * 8]) = zr[j];
    }
    __syncthreads();

    floatx4 acc[4][2];
    #pragma unroll
    for (int mi = 0; mi < 4; ++mi)
        #pragma unroll
        for (int ni = 0; ni < 2; ++ni)
            acc[mi][ni] = (floatx4){0.f, 0.f, 0.f, 0.f};

    #pragma unroll
    for (int kk = 0; kk < 4; ++kk) {
        short8 af[4];
        #pragma unroll
        for (int mi = 0; mi < 4; ++mi)
            af[mi] = *(const short8*)(&As[(mi * 16 + r) * 136 + kk * 32 + q * 8]);
        #pragma unroll
        for (int mi = 0; mi < 4; ++mi) {
            acc[mi][0] = __builtin_amdgcn_mfma_f32_16x16x32_bf16(af[mi], bfw[kk][0], acc[mi][0], 0, 0, 0);
            acc[mi][1] = __builtin_amdgcn_mfma_f32_16x16x32_bf16(af[mi], bfw[kk][1], acc[mi][1], 0, 0, 0);
        }
    }

    float part[4][4];
    #pragma unroll
    for (int mi = 0; mi < 4; ++mi)
        #pragma unroll
        for (int r4 = 0; r4 < 4; ++r4) part[mi][r4] = 0.f;
    #pragma unroll
    for (int mi = 0; mi < 4; ++mi)
        #pragma unroll
        for (int ni = 0; ni < 2; ++ni) {
            int colv = w * 32 + ni * 16 + r;
            float bb = be1f[colv], mm = We2f[colv];
            #pragma unroll
            for (int r4 = 0; r4 < 4; ++r4) {
                float v = acc[mi][ni][r4] + bb;
                part[mi][r4] += fmaxf(v, 0.0f) * mm;
            }
        }
    #pragma unroll
    for (int mi = 0; mi < 4; ++mi)
        #pragma unroll
        for (int r4 = 0; r4 < 4; ++r4) {
            float v = part[mi][r4];
            v += __shfl_xor(v, 1, 64);
            v += __shfl_xor(v, 2, 64);
            v += __shfl_xor(v, 4, 64);
            v += __shfl_xor(v, 8, 64);
            part[mi][r4] = v;
        }
    if (r == 0) {
        #pragma unroll
        for (int mi = 0; mi < 4; ++mi)
            #pragma unroll
            for (int r4 = 0; r4 < 4; ++r4)
                red[w][mi * 16 + q * 4 + r4] = part[mi][r4];
    }
    __syncthreads();
    if (tid < 64) {
        int e = eBase + tid;
        if (e < nE) {
            float s = red[0][tid] + red[1][tid] + red[2][tid] + red[3][tid] + dparams[256];
            float sg = 1.0f / (1.0f + expf(-s));
            if (f) ((float*)dout)[outBase + e] = sg;
            else   ((u16*)dout)[outBase + e] = f2b(sg);
        }
    }
}

// ---------------- launch ----------------

extern "C" void kernel_launch(void* const* d_in, const int* in_sizes, int n_in,
                              void* d_out, int out_size, void* d_ws, size_t ws_size,
                              hipStream_t stream) {
    const void* x   = d_in[0];
    const int* ei   = (const int*)d_in[1];
    const int* pos  = (const int*)d_in[2];
    const int* neg  = (const int*)d_in[3];
    const void* Wl1 = d_in[4];
    const void* bl1 = d_in[5];
    const void* Wr1 = d_in[6];
    const void* g1  = d_in[7];
    const void* b1  = d_in[8];
    const void* Wl2 = d_in[9];
    const void* bl2 = d_in[10];
    const void* Wr2 = d_in[11];
    const void* g2  = d_in[12];
    const void* b2  = d_in[13];
    const void* Wl3 = d_in[14];
    const void* bl3 = d_in[15];
    const void* Wr3 = d_in[16];
    const void* We1 = d_in[17];
    const void* be1 = d_in[18];
    const void* We2 = d_in[19];
    const void* be2 = d_in[20];

    const int N = in_sizes[0] / 128;
    const int E = in_sizes[1] / 2;
    const int nPos = in_sizes[2] / 2;
    const int nNeg = in_sizes[3] / 2;
    const int nbuck = (N + 127) >> 7;
    const int nbuckP = (nbuck + 15) & ~15;     // pad rows to 64B
    const int EPB = 4096;                      // high-TLP CSR build grid
    const int B1 = (E + EPB - 1) / EPB;

    char* p = (char*)d_ws;
    auto alloc = [&](size_t bytes) -> void* {
        void* r = (void*)p;
        p += (bytes + 255) & ~(size_t)255;
        return r;
    };
    int*   flags     = (int*)alloc(64);
    int*   blockhist = (int*)alloc((size_t)B1 * nbuckP * 4);
    int*   coltot    = (int*)alloc((size_t)nbuck * 4);
    int*   bucketbase= (int*)alloc((size_t)nbuck * 4);
    int*   rowptr    = (int*)alloc((size_t)(N + 1) * 4);
    unsigned* pairs  = (unsigned*)alloc((size_t)E * 4);
    int*   colbuf    = (int*)alloc((size_t)E * 4);
    u16*   xb      = (u16*)alloc((size_t)N * 128 * 2);   // reused as hbufB
    u16*   hbufA   = (u16*)alloc((size_t)N * 128 * 2);   // reused as zbuf
    u16*   meanbuf = (u16*)alloc((size_t)N * 128 * 2);   // reused as ubuf
    u8*    x8      = (u8*)alloc((size_t)N * 128);
    u8*    h8      = (u8*)alloc((size_t)N * 128);
    u8*    t8      = (u8*)alloc((size_t)N * 64);
    u16*   Wcat1   = (u16*)alloc((size_t)256 * 128 * 2);
    u16*   Wcat2   = (u16*)alloc((size_t)256 * 128 * 2);
    u16*   Wcat3   = (u16*)alloc((size_t)128 * 128 * 2);
    u16*   Web     = (u16*)alloc((size_t)128 * 128 * 2);
    float* al1 = (float*)alloc(128 * 4);
    float* bt1 = (float*)alloc(128 * 4);
    float* al2 = (float*)alloc(128 * 4);
    float* bt2 = (float*)alloc(128 * 4);
    float* al3 = (float*)alloc(128 * 4);
    float* bt3 = (float*)alloc(128 * 4);
    float* dparams = (float*)alloc(260 * 4);
    u16* hbufB = xb;
    u16* ubuf  = meanbuf + (size_t)N * 64;   // meanbuf free after gemm2
    u16* zbuf  = hbufA + (size_t)N * 64;     // hbufA free after gemm2

    // dtype sniff + bucketed CSR build (no global atomics)
    sniff_kernel<<<1, 256, 0, stream>>>((const unsigned*)x, ei, flags);
    bucket_count_kernel<<<B1, 256, 0, stream>>>(ei, blockhist, E, EPB, nbuckP, nbuck, flags);
    colscan_kernel<<<nbuck, 64, 0, stream>>>(blockhist, coltot, B1, nbuckP);
    base_scan_kernel<<<1, 1024, 0, stream>>>(coltot, bucketbase, rowptr + N, nbuck, E);
    bucket_scatter_kernel<<<B1, 256, 0, stream>>>(ei, bucketbase, blockhist, pairs, E, EPB, nbuckP, nbuck, flags);
    bucket_csr_kernel<<<nbuck, 256, 0, stream>>>(pairs, bucketbase, coltot, rowptr, colbuf, N);

    // input / parameter conversion
    cvt_x_kernel<<<(N * 64 + 255) / 256, 256, 0, stream>>>(x, xb, (u16*)x8, flags, N * 64);
    prep_all_kernel<<<(66048 + 255) / 256, 256, 0, stream>>>(
        Wl1, Wr1, Wcat1, Wl2, Wr2, Wcat2, Wl3, Wr3, Wcat3, We1, Web,
        g1, b1, bl1, al1, bt1, g2, b2, bl2, al2, bt2, bl3, al3, bt3,
        be1, We2, be2, dparams, flags);

    int gB = (N + 63) / 64;
    size_t lds256 = (size_t)64 * (256 + 8) * 2;
    size_t lds128 = (size_t)64 * (128 + 8) * 2;

    // layer 1: mean from x8; h1 = relu(bn([mean|x]@W1)) + x -> hbufA (bf16) + h8 (fp8)
    aggregate_fp8_kernel<128><<<(N + 31) / 32, 256, 0, stream>>>(x8, rowptr, colbuf, meanbuf, N);
    gemm_sage_kernel<256><<<gB, 256, lds256, stream>>>(meanbuf, xb, Wcat1, al1, bt1,
                                                       1, hbufA, 128, nullptr, h8, 128, N, 1);
    // layer 2: mean from h8; h2 -> hbufB (bf16 only)
    aggregate_fp8_kernel<128><<<(N + 31) / 32, 256, 0, stream>>>(h8, rowptr, colbuf, meanbuf, N);
    gemm_sage_kernel<256><<<gB, 256, lds256, stream>>>(meanbuf, hbufA, Wcat2, al2, bt2,
                                                       1, hbufB, 128, nullptr, nullptr, 0, N, 1);
    // layer 3 (commuted): [t|u] = h2@[Wl3|Wr3]; t -> t8 (fp8), u -> ubuf (bf16)
    gemm_sage_kernel<128><<<gB, 256, lds128, stream>>>(hbufB, hbufB, Wcat3, al3, bt3,
                                                       0, nullptr, 0, ubuf, t8, 64, N, 0);
    // z = mean(t8) + u -> zbuf + d_out
    agg_combine_kernel<<<(N + 63) / 64, 256, 0, stream>>>(t8, rowptr, colbuf, ubuf, zbuf,
                                                          d_out, N, flags);

    // decode pos + neg in one launch (64 edges/block)
    long long posBase = (long long)N * 64;
    int bP = (nPos + 63) / 64, bN = (nNeg + 63) / 64;
    decode_kernel<<<bP + bN, 256, 0, stream>>>(zbuf, pos, neg, nPos, nNeg, bP,
                                               Web, dparams, d_out, posBase, flags);
}

// Round 18
// 441.396 us; speedup vs baseline: 1.0428x; 1.0090x over previous
//
#include <hip/hip_runtime.h>
#include <hip/hip_bf16.h>

typedef unsigned short u16;
typedef unsigned char u8;
typedef short short8 __attribute__((ext_vector_type(8)));
typedef float floatx4 __attribute__((ext_vector_type(4)));
typedef float floatx2 __attribute__((ext_vector_type(2)));

__device__ __forceinline__ float b2f(u16 u) {
    unsigned v = ((unsigned)u) << 16;
    float f;
    __builtin_memcpy(&f, &v, 4);
    return f;
}
__device__ __forceinline__ float b2f_lo(unsigned w) { return b2f((u16)(w & 0xffffu)); }
__device__ __forceinline__ float b2f_hi(unsigned w) { return b2f((u16)(w >> 16)); }
__device__ __forceinline__ u16 f2b(float f) {
    unsigned u;
    __builtin_memcpy(&u, &f, 4);
    u = u + 0x7fffu + ((u >> 16) & 1u);
    return (u16)(u >> 16);
}
__device__ __forceinline__ unsigned pack2(float a, float b) {
    return (unsigned)f2b(a) | ((unsigned)f2b(b) << 16);
}
__device__ __forceinline__ float loadp(const void* p, int i, int f) {
    return f ? ((const float*)p)[i] : b2f(((const u16*)p)[i]);
}
__device__ __forceinline__ u8 f2e4m3(float v) {
    int r = __builtin_amdgcn_cvt_pk_fp8_f32(v, v, 0, false);
    return (u8)(r & 0xff);
}
// accumulate 16 fp8 values (one uint4) into a[16]
__device__ __forceinline__ void acc16_fp8(float* a, uint4 p) {
    floatx2 f;
    f = __builtin_amdgcn_cvt_pk_f32_fp8((int)p.x, false); a[0] += f[0];  a[1] += f[1];
    f = __builtin_amdgcn_cvt_pk_f32_fp8((int)p.x, true);  a[2] += f[0];  a[3] += f[1];
    f = __builtin_amdgcn_cvt_pk_f32_fp8((int)p.y, false); a[4] += f[0];  a[5] += f[1];
    f = __builtin_amdgcn_cvt_pk_f32_fp8((int)p.y, true);  a[6] += f[0];  a[7] += f[1];
    f = __builtin_amdgcn_cvt_pk_f32_fp8((int)p.z, false); a[8] += f[0];  a[9] += f[1];
    f = __builtin_amdgcn_cvt_pk_f32_fp8((int)p.z, true);  a[10] += f[0]; a[11] += f[1];
    f = __builtin_amdgcn_cvt_pk_f32_fp8((int)p.w, false); a[12] += f[0]; a[13] += f[1];
    f = __builtin_amdgcn_cvt_pk_f32_fp8((int)p.w, true);  a[14] += f[0]; a[15] += f[1];
}

// ---------------- dtype sniffing ----------------
__global__ void sniff_kernel(const unsigned* __restrict__ xw, const int* __restrict__ eiw,
                             int* __restrict__ flags) {
    __shared__ int s_fp32, s_i64;
    if (threadIdx.x == 0) { s_fp32 = 0; s_i64 = 1; }
    __syncthreads();
    int t = threadIdx.x;  // 256 threads
    unsigned w = xw[t];
    float lo = b2f_lo(w);
    if (!(fabsf(lo) <= 64.0f)) atomicOr(&s_fp32, 1);   // also catches NaN
    if (eiw[2 * t + 1] != 0) atomicAnd(&s_i64, 0);
    __syncthreads();
    if (t == 0) { flags[0] = s_fp32; flags[1] = s_i64; }
}

// ---------------- input conversion (bf16 + fp8 shadow) ----------------
__global__ void cvt_x_kernel(const void* __restrict__ x, u16* __restrict__ xb,
                             u16* __restrict__ x8,   // fp8 pairs stored as u16
                             const int* __restrict__ flags, int nPairs) {
    int f = flags[0];
    int i = blockIdx.x * 256 + threadIdx.x;
    if (i >= nPairs) return;
    float lo, hi;
    if (f) {
        float2 v = ((const float2*)x)[i];
        lo = v.x; hi = v.y;
        ((unsigned*)xb)[i] = pack2(lo, hi);
    } else {
        unsigned w = ((const unsigned*)x)[i];
        lo = b2f_lo(w); hi = b2f_hi(w);
        ((unsigned*)xb)[i] = w;
    }
    int r = __builtin_amdgcn_cvt_pk_fp8_f32(lo, hi, 0, false);
    x8[i] = (u16)(r & 0xffff);
}

// ---------------- fused parameter prep (one launch) ----------------
__global__ void prep_all_kernel(const void* Wl1, const void* Wr1, u16* __restrict__ Wcat1,
                                const void* Wl2, const void* Wr2, u16* __restrict__ Wcat2,
                                const void* Wl3, const void* Wr3, u16* __restrict__ Wcat3,
                                const void* We1, u16* __restrict__ Web,
                                const void* g1, const void* b1, const void* bl1,
                                float* __restrict__ al1, float* __restrict__ bt1,
                                const void* g2, const void* b2, const void* bl2,
                                float* __restrict__ al2, float* __restrict__ bt2,
                                const void* bl3,
                                float* __restrict__ al3, float* __restrict__ bt3,
                                const void* be1, const void* We2, const void* be2,
                                float* __restrict__ dparams,
                                const int* __restrict__ flags) {
    int f = flags[0];
    int idx = blockIdx.x * 256 + threadIdx.x;
    if (idx < 16384) {
        int k = idx >> 7, n = idx & 127;           // Wl1/Wr1: [k=128][n=128]
        Wcat1[n * 256 + k]       = f ? f2b(((const float*)Wl1)[idx]) : ((const u16*)Wl1)[idx];
        Wcat1[n * 256 + 128 + k] = f ? f2b(((const float*)Wr1)[idx]) : ((const u16*)Wr1)[idx];
    } else if (idx < 32768) {
        int i = idx - 16384;
        int k = i >> 7, n = i & 127;
        Wcat2[n * 256 + k]       = f ? f2b(((const float*)Wl2)[i]) : ((const u16*)Wl2)[i];
        Wcat2[n * 256 + 128 + k] = f ? f2b(((const float*)Wr2)[i]) : ((const u16*)Wr2)[i];
    } else if (idx < 49152) {
        int i = idx - 32768;
        int k = i >> 7, n = i & 127;               // combined [k=128][n=128], n<64 Wl3 else Wr3
        const void* src = (n < 64) ? Wl3 : Wr3;
        int j = k * 64 + (n & 63);
        Wcat3[n * 128 + k] = f ? f2b(((const float*)src)[j]) : ((const u16*)src)[j];
    } else if (idx < 65536) {
        int i = idx - 49152;
        int k = i >> 7, n = i & 127;               // We1: [k=128][n=128]
        Web[n * 128 + k] = f ? f2b(((const float*)We1)[i]) : ((const u16*)We1)[i];
    } else {
        int i = idx - 65536;
        if (i < 128) {
            float s = loadp(g1, i, f) * rsqrtf(1.0f + 1e-5f);
            al1[i] = s;
            bt1[i] = loadp(bl1, i, f) * s + loadp(b1, i, f);
        } else if (i < 256) {
            int j = i - 128;
            float s = loadp(g2, j, f) * rsqrtf(1.0f + 1e-5f);
            al2[j] = s;
            bt2[j] = loadp(bl2, j, f) * s + loadp(b2, j, f);
        } else if (i < 384) {
            int j = i - 256;
            al3[j] = 1.0f;
            bt3[j] = (j < 64) ? 0.0f : loadp(bl3, j - 64, f);
        } else if (i < 512) {
            int j = i - 384;
            dparams[j] = loadp(be1, j, f);
            dparams[128 + j] = loadp(We2, j, f);
            if (j == 0) dparams[256] = loadp(be2, 0, f);
        }
    }
}

// ---------------- CSR build: two-level counting sort (no global atomics) ----------------
// blockhist layout [b][nbuckP]: count-write and scatter-read are COALESCED.
// pairs packed to 4B: src | (d&127)<<25  (valid for N < 2^25).
__device__ __forceinline__ int edge_at(const int* ei, long long idx, int i64) {
    return i64 ? ei[2 * idx] : ei[idx];
}

__global__ __launch_bounds__(256) void bucket_count_kernel(const int* __restrict__ ei,
                                                           int* __restrict__ blockhist,
                                                           int E, int EPB, int nbuckP, int nbuck,
                                                           const int* __restrict__ flags) {
    __shared__ int hist[1024];
    for (int i = threadIdx.x; i < nbuck; i += 256) hist[i] = 0;
    __syncthreads();
    int i64 = flags[1];
    int b = blockIdx.x;
    int lo = b * EPB, hi = min(lo + EPB, E);
    for (int e = lo + (int)threadIdx.x; e < hi; e += 256) {
        int d = edge_at(ei, (long long)E + e, i64);
        atomicAdd(&hist[d >> 7], 1);
    }
    __syncthreads();
    for (int k = threadIdx.x; k < nbuck; k += 256)
        blockhist[(size_t)b * nbuckP + k] = hist[k];
}

// looped 64-wide exclusive scan (over blocks b) with carry; strided reads, high TLP
__global__ __launch_bounds__(64) void colscan_kernel(int* __restrict__ blockhist,
                                                     int* __restrict__ coltot,
                                                     int B1, int nbuckP) {
    int k = blockIdx.x, l = threadIdx.x;
    int carry = 0;
    for (int base = 0; base < B1; base += 64) {
        int idx = base + l;
        int x = (idx < B1) ? blockhist[(size_t)idx * nbuckP + k] : 0;
        int s = x;
        #pragma unroll
        for (int off = 1; off < 64; off <<= 1) {
            int u = __shfl_up(s, off, 64);
            if (l >= off) s += u;
        }
        if (idx < B1) blockhist[(size_t)idx * nbuckP + k] = carry + s - x;
        carry += __shfl(s, 63, 64);
    }
    if (l == 0) coltot[k] = carry;
}

__global__ __launch_bounds__(1024) void base_scan_kernel(const int* __restrict__ coltot,
                                                         int* __restrict__ bucketbase,
                                                         int* __restrict__ rowptrN,
                                                         int nbuck, int E) {
    __shared__ int wsum[16];
    int t = threadIdx.x, lane = t & 63, w = t >> 6;
    int v = (t < nbuck) ? coltot[t] : 0;
    int inc = v;
    #pragma unroll
    for (int off = 1; off < 64; off <<= 1) {
        int u = __shfl_up(inc, off, 64);
        if (lane >= off) inc += u;
    }
    if (lane == 63) wsum[w] = inc;
    __syncthreads();
    int add = 0;
    for (int i = 0; i < w; ++i) add += wsum[i];
    if (t < nbuck) bucketbase[t] = add + inc - v;
    if (t == 0) rowptrN[0] = E;
}

__global__ __launch_bounds__(256) void bucket_scatter_kernel(const int* __restrict__ ei,
                                                             const int* __restrict__ bucketbase,
                                                             const int* __restrict__ blockhist,
                                                             unsigned* __restrict__ pairs,
                                                             int E, int EPB, int nbuckP, int nbuck,
                                                             const int* __restrict__ flags) {
    __shared__ int off[1024];
    int b = blockIdx.x;
    for (int k = threadIdx.x; k < nbuck; k += 256)
        off[k] = bucketbase[k] + blockhist[(size_t)b * nbuckP + k];
    __syncthreads();
    int i64 = flags[1];
    int lo = b * EPB, hi = min(lo + EPB, E);
    for (int e = lo + (int)threadIdx.x; e < hi; e += 256) {
        int s = edge_at(ei, e, i64);
        int d = edge_at(ei, (long long)E + e, i64);
        int slot = atomicAdd(&off[d >> 7], 1);
        pairs[slot] = (unsigned)s | ((unsigned)(d & 127) << 25);
    }
}

__global__ __launch_bounds__(256) void bucket_csr_kernel(const unsigned* __restrict__ pairs,
                                                         const int* __restrict__ bucketbase,
                                                         const int* __restrict__ coltot,
                                                         int* __restrict__ rowptr,
                                                         int* __restrict__ col, int N) {
    __shared__ unsigned pk[4096];
    __shared__ int hist[128], cur[128];
    int k = blockIdx.x, tid = threadIdx.x;
    if (tid < 128) hist[tid] = 0;
    __syncthreads();
    int base = bucketbase[k], cnt = coltot[k];
    int staged = min(cnt, 4096);
    for (int i = tid; i < cnt; i += 256) {
        unsigned pv = pairs[base + i];
        int j = (int)(pv >> 25);
        atomicAdd(&hist[j], 1);
        if (i < 4096) pk[i] = pv;
    }
    __syncthreads();
    if (tid < 64) {
        int x0 = hist[tid], x1 = hist[64 + tid];
        int s0 = x0;
        #pragma unroll
        for (int off = 1; off < 64; off <<= 1) {
            int u = __shfl_up(s0, off, 64);
            if (tid >= off) s0 += u;
        }
        int tot0 = __shfl(s0, 63, 64);
        int s1 = x1;
        #pragma unroll
        for (int off = 1; off < 64; off <<= 1) {
            int u = __shfl_up(s1, off, 64);
            if (tid >= off) s1 += u;
        }
        s1 += tot0;
        cur[tid] = s0 - x0;
        cur[64 + tid] = s1 - x1;
    }
    __syncthreads();
    int node0 = k << 7;
    if (tid < 128 && node0 + tid < N) rowptr[node0 + tid] = base + cur[tid];
    __syncthreads();
    for (int i = tid; i < staged; i += 256) {
        unsigned pv = pk[i];
        int slot = base + atomicAdd(&cur[pv >> 25], 1);
        col[slot] = (int)(pv & 0x1FFFFFFu);
    }
    for (int i = 4096 + tid; i < cnt; i += 256) {
        unsigned pv = pairs[base + i];
        int slot = base + atomicAdd(&cur[pv >> 25], 1);
        col[slot] = (int)(pv & 0x1FFFFFFu);
    }
}

// ---------------- mean aggregation over fp8 rows -> bf16 means ----------------
// 8-deep independent gather unroll for memory-level parallelism (latency-bound regime).
template <int CH>
__global__ __launch_bounds__(256) void aggregate_fp8_kernel(const u8* __restrict__ X8,
                                                            const int* __restrict__ rowptr,
                                                            const int* __restrict__ col,
                                                            u16* __restrict__ meanout, int N) {
    constexpr int LPR = CH / 16;
    constexpr int GPB = 256 / LPR;
    int t = threadIdx.x;
    int g = t / LPR;
    int o = t % LPR;
    int u = blockIdx.x * GPB + g;
    if (u >= N) return;
    const uint4* Xv = (const uint4*)X8;
    int beg = rowptr[u], end = rowptr[u + 1];
    float a[16];
    #pragma unroll
    for (int i = 0; i < 16; ++i) a[i] = 0.f;
    int e = beg;
    for (; e + 8 <= end; e += 8) {
        uint4 p0 = Xv[(size_t)col[e]     * LPR + o];
        uint4 p1 = Xv[(size_t)col[e + 1] * LPR + o];
        uint4 p2 = Xv[(size_t)col[e + 2] * LPR + o];
        uint4 p3 = Xv[(size_t)col[e + 3] * LPR + o];
        uint4 p4 = Xv[(size_t)col[e + 4] * LPR + o];
        uint4 p5 = Xv[(size_t)col[e + 5] * LPR + o];
        uint4 p6 = Xv[(size_t)col[e + 6] * LPR + o];
        uint4 p7 = Xv[(size_t)col[e + 7] * LPR + o];
        acc16_fp8(a, p0); acc16_fp8(a, p1); acc16_fp8(a, p2); acc16_fp8(a, p3);
        acc16_fp8(a, p4); acc16_fp8(a, p5); acc16_fp8(a, p6); acc16_fp8(a, p7);
    }
    for (; e + 4 <= end; e += 4) {
        uint4 p0 = Xv[(size_t)col[e]     * LPR + o];
        uint4 p1 = Xv[(size_t)col[e + 1] * LPR + o];
        uint4 p2 = Xv[(size_t)col[e + 2] * LPR + o];
        uint4 p3 = Xv[(size_t)col[e + 3] * LPR + o];
        acc16_fp8(a, p0); acc16_fp8(a, p1); acc16_fp8(a, p2); acc16_fp8(a, p3);
    }
    for (; e < end; ++e) {
        uint4 p = Xv[(size_t)col[e] * LPR + o];
        acc16_fp8(a, p);
    }
    int deg = end - beg;
    float inv = (deg > 0) ? 1.0f / (float)deg : 0.0f;
    uint4 ov0, ov1;
    ov0.x = pack2(a[0] * inv, a[1] * inv);   ov0.y = pack2(a[2] * inv, a[3] * inv);
    ov0.z = pack2(a[4] * inv, a[5] * inv);   ov0.w = pack2(a[6] * inv, a[7] * inv);
    ov1.x = pack2(a[8] * inv, a[9] * inv);   ov1.y = pack2(a[10] * inv, a[11] * inv);
    ov1.z = pack2(a[12] * inv, a[13] * inv); ov1.w = pack2(a[14] * inv, a[15] * inv);
    uint4* mo = (uint4*)meanout;
    mo[(size_t)u * (CH / 8) + o * 2 + 0] = ov0;
    mo[(size_t)u * (CH / 8) + o * 2 + 1] = ov1;
}

// ---------------- fused layer-3 tail: z = mean_fp8(t8) + u ; write zbuf + d_out ----------------
__global__ __launch_bounds__(256) void agg_combine_kernel(const u8* __restrict__ T8,
                                                          const int* __restrict__ rowptr,
                                                          const int* __restrict__ col,
                                                          const u16* __restrict__ ubuf,
                                                          u16* __restrict__ zbuf,
                                                          void* __restrict__ dout,
                                                          int N, const int* __restrict__ flags) {
    constexpr int LPR = 4;           // 64 ch / 16
    constexpr int GPB = 64;
    int f = flags[0];
    int t = threadIdx.x;
    int g = t / LPR;
    int o = t % LPR;
    int u = blockIdx.x * GPB + g;
    if (u >= N) return;
    const uint4* Xv = (const uint4*)T8;
    int beg = rowptr[u], end = rowptr[u + 1];
    float a[16];
    #pragma unroll
    for (int i = 0; i < 16; ++i) a[i] = 0.f;
    int e = beg;
    for (; e + 8 <= end; e += 8) {
        uint4 p0 = Xv[(size_t)col[e]     * LPR + o];
        uint4 p1 = Xv[(size_t)col[e + 1] * LPR + o];
        uint4 p2 = Xv[(size_t)col[e + 2] * LPR + o];
        uint4 p3 = Xv[(size_t)col[e + 3] * LPR + o];
        uint4 p4 = Xv[(size_t)col[e + 4] * LPR + o];
        uint4 p5 = Xv[(size_t)col[e + 5] * LPR + o];
        uint4 p6 = Xv[(size_t)col[e + 6] * LPR + o];
        uint4 p7 = Xv[(size_t)col[e + 7] * LPR + o];
        acc16_fp8(a, p0); acc16_fp8(a, p1); acc16_fp8(a, p2); acc16_fp8(a, p3);
        acc16_fp8(a, p4); acc16_fp8(a, p5); acc16_fp8(a, p6); acc16_fp8(a, p7);
    }
    for (; e + 4 <= end; e += 4) {
        uint4 p0 = Xv[(size_t)col[e]     * LPR + o];
        uint4 p1 = Xv[(size_t)col[e + 1] * LPR + o];
        uint4 p2 = Xv[(size_t)col[e + 2] * LPR + o];
        uint4 p3 = Xv[(size_t)col[e + 3] * LPR + o];
        acc16_fp8(a, p0); acc16_fp8(a, p1); acc16_fp8(a, p2); acc16_fp8(a, p3);
    }
    for (; e < end; ++e) {
        uint4 p = Xv[(size_t)col[e] * LPR + o];
        acc16_fp8(a, p);
    }
    int deg = end - beg;
    float inv = (deg > 0) ? 1.0f / (float)deg : 0.0f;
    const uint4* uv = (const uint4*)(ubuf + (size_t)u * 64 + o * 16);
    uint4 u0 = uv[0], u1 = uv[1];
    float z[16];
    z[0] = a[0] * inv + b2f_lo(u0.x);  z[1] = a[1] * inv + b2f_hi(u0.x);
    z[2] = a[2] * inv + b2f_lo(u0.y);  z[3] = a[3] * inv + b2f_hi(u0.y);
    z[4] = a[4] * inv + b2f_lo(u0.z);  z[5] = a[5] * inv + b2f_hi(u0.z);
    z[6] = a[6] * inv + b2f_lo(u0.w);  z[7] = a[7] * inv + b2f_hi(u0.w);
    z[8] = a[8] * inv + b2f_lo(u1.x);  z[9] = a[9] * inv + b2f_hi(u1.x);
    z[10] = a[10] * inv + b2f_lo(u1.y); z[11] = a[11] * inv + b2f_hi(u1.y);
    z[12] = a[12] * inv + b2f_lo(u1.z); z[13] = a[13] * inv + b2f_hi(u1.z);
    z[14] = a[14] * inv + b2f_lo(u1.w); z[15] = a[15] * inv + b2f_hi(u1.w);
    uint4 zv0, zv1;
    zv0.x = pack2(z[0], z[1]);   zv0.y = pack2(z[2], z[3]);
    zv0.z = pack2(z[4], z[5]);   zv0.w = pack2(z[6], z[7]);
    zv1.x = pack2(z[8], z[9]);   zv1.y = pack2(z[10], z[11]);
    zv1.z = pack2(z[12], z[13]); zv1.w = pack2(z[14], z[15]);
    uint4* zo = (uint4*)(zbuf + (size_t)u * 64 + o * 16);
    zo[0] = zv0; zo[1] = zv1;
    if (f) {
        float* fo = (float*)dout + (size_t)u * 64 + o * 16;
        #pragma unroll
        for (int i = 0; i < 16; ++i) fo[i] = z[i];
    } else {
        uint4* bo = (uint4*)((u16*)dout + (size_t)u * 64 + o * 16);
        bo[0] = zv0; bo[1] = zv1;
    }
}

// ---------------- fused SAGE-layer GEMM (templated K, register-held B, single barrier) ----------------
// A-tile staged via global_load_lds width=16 (direct HBM->LDS DMA, no VGPR round-trip).
// LDS is LINEAR [64][K] (global_load_lds requires contiguous dest); bank conflicts on
// the fragment reads are fixed by the st-style XOR swizzle: LDS 16B-chunk c of row r
// holds GLOBAL chunk c^(r&7) (pre-swizzled per-lane source address, m201/m173 pattern);
// every LDS read applies the same XOR. OOB tail rows load garbage (reads stay in d_ws);
// safe: MFMA rows are independent and all consumers are row<M-guarded.
template <int K>
__global__ __launch_bounds__(256) void gemm_sage_kernel(
    const u16* __restrict__ A1, const u16* __restrict__ A2,
    const u16* __restrict__ WT,
    const float* __restrict__ alpha, const float* __restrict__ beta,
    int addRes, u16* __restrict__ out, int ldo, u16* __restrict__ outB,
    u8* __restrict__ out8, int ld8,
    int M, int relu) {
    extern __shared__ u16 As[];          // 64 x K (linear, swizzled content)
    constexpr int NK = K / 32;
    constexpr int NCH = K / 8;           // 16B chunks per row
    constexpr int RPI = 64 / NCH;        // rows per wave-iteration (2 for K=256, 4 for K=128)
    constexpr int J = NCH / 4;           // staging iterations per wave
    int tid = threadIdx.x;
    int mBase = blockIdx.x * 64;
    int lane = tid & 63, w = tid >> 6;
    int q = lane >> 4, r = lane & 15;

    // ---- prefetch ALL B fragments into registers (L2-hot; overlaps A staging) ----
    short8 bq[NK][2];
    {
        const u16* wr0 = WT + (size_t)(w * 32 + r) * K + q * 8;
        const u16* wr1 = WT + (size_t)(w * 32 + 16 + r) * K + q * 8;
        #pragma unroll
        for (int kk = 0; kk < NK; ++kk) {
            bq[kk][0] = *(const short8*)(wr0 + kk * 32);
            bq[kk][1] = *(const short8*)(wr1 + kk * 32);
        }
    }

    // ---- stage full A tile via global_load_lds (pre-swizzled source) ----
    {
        int c = lane & (NCH - 1);        // chunk within row
        int rsub = lane / NCH;           // row within 1KB wave-chunk
        #pragma unroll
        for (int j = 0; j < J; ++j) {
            int blk = w * J + j;         // 1KB LDS block index (wave-uniform)
            int row = blk * RPI + rsub;
            int gr = mBase + row;
            int gc = c ^ (row & 7);      // global chunk to fetch into LDS chunk c
            const u16* src;
            if (K == 256) {
                src = (gc < 16) ? (A1 + (size_t)gr * 128 + gc * 8)
                                : (A2 + (size_t)gr * 128 + (gc - 16) * 8);
            } else {
                src = A1 + (size_t)gr * 128 + gc * 8;
            }
            __builtin_amdgcn_global_load_lds(src, (u16*)As + (size_t)blk * 512, 16, 0, 0);
        }
    }
    __syncthreads();

    floatx4 acc[4][2];
    #pragma unroll
    for (int mi = 0; mi < 4; ++mi)
        #pragma unroll
        for (int ni = 0; ni < 2; ++ni)
            acc[mi][ni] = (floatx4){0.f, 0.f, 0.f, 0.f};

    #pragma unroll
    for (int kk = 0; kk < NK; ++kk) {
        short8 af[4];
        #pragma unroll
        for (int mi = 0; mi < 4; ++mi) {
            int R = mi * 16 + r;
            int sc = (kk * 4 + q) ^ (r & 7);     // swizzled chunk
            af[mi] = *(const short8*)(&As[(size_t)R * K + sc * 8]);
        }
        #pragma unroll
        for (int mi = 0; mi < 4; ++mi) {
            acc[mi][0] = __builtin_amdgcn_mfma_f32_16x16x32_bf16(af[mi], bq[kk][0], acc[mi][0], 0, 0, 0);
            acc[mi][1] = __builtin_amdgcn_mfma_f32_16x16x32_bf16(af[mi], bq[kk][1], acc[mi][1], 0, 0, 0);
        }
    }

    #pragma unroll
    for (int mi = 0; mi < 4; ++mi)
        #pragma unroll
        for (int ni = 0; ni < 2; ++ni) {
            int colv = w * 32 + ni * 16 + r;
            float al = alpha[colv], be = beta[colv];
            #pragma unroll
            for (int r4 = 0; r4 < 4; ++r4) {
                int lrow = mi * 16 + q * 4 + r4;
                int row = mBase + lrow;
                if (row < M) {
                    float v = acc[mi][ni][r4] * al + be;
                    if (relu) v = fmaxf(v, 0.0f);
                    if (K > 128 && addRes) {
                        int sce = (16 + (colv >> 3)) ^ (lrow & 7);
                        v += b2f(As[(size_t)lrow * K + sce * 8 + (colv & 7)]);
                    }
                    if (outB) {
                        if (colv < 64) out8[(size_t)row * 64 + colv] = f2e4m3(v);
                        else outB[(size_t)row * 64 + (colv - 64)] = f2b(v);
                    } else {
                        out[(size_t)row * ldo + colv] = f2b(v);
                        if (out8) out8[(size_t)row * ld8 + colv] = f2e4m3(v);
                    }
                }
            }
        }
}

// ---------------- fused edge decoder (64 edges/block, pos+neg merged, wn-split) ----------------
__global__ __launch_bounds__(256) void decode_kernel(
    const u16* __restrict__ z,
    const int* __restrict__ pos, const int* __restrict__ neg,
    int nPos, int nNeg, int blocksPos,
    const u16* __restrict__ WebT,
    const float* __restrict__ dparams,
    void* __restrict__ dout, long long posBase,
    const int* __restrict__ flags) {
    __shared__ u16 As[64 * 136];
    __shared__ float red[4][64];
    __shared__ float be1f[128], We2f[128];
    int tid = threadIdx.x;
    int f = flags[0];
    int b = blockIdx.x;
    const int* sidx; const int* didx; int nE; long long outBase; int eBase;
    if (b < blocksPos) {
        sidx = pos; didx = pos + nPos; nE = nPos; outBase = posBase; eBase = b * 64;
    } else {
        sidx = neg; didx = neg + nNeg; nE = nNeg; outBase = posBase + nPos;
        eBase = (b - blocksPos) * 64;
    }

    int lane = tid & 63, w = tid >> 6;
    int q = lane >> 4, r = lane & 15;

    // ---- issue z-gather first (latency overlapped with weight loads below) ----
    short8 zr[4];
    {
        int row = tid >> 2, ch = tid & 3;
        int e = eBase + row;
        if (e >= nE) e = nE - 1;
        int node = (ch < 2) ? sidx[e] : didx[e];
        int off = (ch & 1) * 32;
        const short8* src = (const short8*)(z + (size_t)node * 64 + off);
        #pragma unroll
        for (int j = 0; j < 4; ++j) zr[j] = src[j];
    }

    if (tid < 128) { be1f[tid] = dparams[tid]; We2f[tid] = dparams[128 + tid]; }

    // ---- B-fragments: held in registers, WebT read exactly once per block ----
    short8 bfw[4][2];   // [k0/32][ni]
    {
        const u16* w0 = WebT + (size_t)(w * 32 + r) * 128 + q * 8;
        const u16* w1 = WebT + (size_t)(w * 32 + 16 + r) * 128 + q * 8;
        #pragma unroll
        for (int kk = 0; kk < 4; ++kk) {
            bfw[kk][0] = *(const short8*)(w0 + kk * 32);
            bfw[kk][1] = *(const short8*)(w1 + kk * 32);
        }
    }

    // ---- write staged z rows to LDS ----
    {
        int row = tid >> 2, ch = tid & 3;
        #pragma unroll
        for (int j = 0; j < 4; ++j)
            *(short8*)(&As[row * 136 + ch * 32 + j * 8]) = zr[j];
    }
    __syncthreads();

    floatx4 acc[4][2];
    #pragma unroll
    for (int mi = 0; mi < 4; ++mi)
        #pragma unroll
        for (int ni = 0; ni < 2; ++ni)
            acc[mi][ni] = (floatx4){0.f, 0.f, 0.f, 0.f};

    #pragma unroll
    for (int kk = 0; kk < 4; ++kk) {
        short8 af[4];
        #pragma unroll
        for (int mi = 0; mi < 4; ++mi)
            af[mi] = *(const short8*)(&As[(mi * 16 + r) * 136 + kk * 32 + q * 8]);
        #pragma unroll
        for (int mi = 0; mi < 4; ++mi) {
            acc[mi][0] = __builtin_amdgcn_mfma_f32_16x16x32_bf16(af[mi], bfw[kk][0], acc[mi][0], 0, 0, 0);
            acc[mi][1] = __builtin_amdgcn_mfma_f32_16x16x32_bf16(af[mi], bfw[kk][1], acc[mi][1], 0, 0, 0);
        }
    }

    float part[4][4];
    #pragma unroll
    for (int mi = 0; mi < 4; ++mi)
        #pragma unroll
        for (int r4 = 0; r4 < 4; ++r4) part[mi][r4] = 0.f;
    #pragma unroll
    for (int mi = 0; mi < 4; ++mi)
        #pragma unroll
        for (int ni = 0; ni < 2; ++ni) {
            int colv = w * 32 + ni * 16 + r;
            float bb = be1f[colv], mm = We2f[colv];
            #pragma unroll
            for (int r4 = 0; r4 < 4; ++r4) {
                float v = acc[mi][ni][r4] + bb;
                part[mi][r4] += fmaxf(v, 0.0f) * mm;
            }
        }
    #pragma unroll
    for (int mi = 0; mi < 4; ++mi)
        #pragma unroll
        for (int r4 = 0; r4 < 4; ++r4) {
            float v = part[mi][r4];
            v += __shfl_xor(v, 1, 64);
            v += __shfl_xor(v, 2, 64);
            v += __shfl_xor(v, 4, 64);
            v += __shfl_xor(v, 8, 64);
            part[mi][r4] = v;
        }
    if (r == 0) {
        #pragma unroll
        for (int mi = 0; mi < 4; ++mi)
            #pragma unroll
            for (int r4 = 0; r4 < 4; ++r4)
                red[w][mi * 16 + q * 4 + r4] = part[mi][r4];
    }
    __syncthreads();
    if (tid < 64) {
        int e = eBase + tid;
        if (e < nE) {
            float s = red[0][tid] + red[1][tid] + red[2][tid] + red[3][tid] + dparams[256];
            float sg = 1.0f / (1.0f + expf(-s));
            if (f) ((float*)dout)[outBase + e] = sg;
            else   ((u16*)dout)[outBase + e] = f2b(sg);
        }
    }
}

// ---------------- launch ----------------

extern "C" void kernel_launch(void* const* d_in, const int* in_sizes, int n_in,
                              void* d_out, int out_size, void* d_ws, size_t ws_size,
                              hipStream_t stream) {
    const void* x   = d_in[0];
    const int* ei   = (const int*)d_in[1];
    const int* pos  = (const int*)d_in[2];
    const int* neg  = (const int*)d_in[3];
    const void* Wl1 = d_in[4];
    const void* bl1 = d_in[5];
    const void* Wr1 = d_in[6];
    const void* g1  = d_in[7];
    const void* b1  = d_in[8];
    const void* Wl2 = d_in[9];
    const void* bl2 = d_in[10];
    const void* Wr2 = d_in[11];
    const void* g2  = d_in[12];
    const void* b2  = d_in[13];
    const void* Wl3 = d_in[14];
    const void* bl3 = d_in[15];
    const void* Wr3 = d_in[16];
    const void* We1 = d_in[17];
    const void* be1 = d_in[18];
    const void* We2 = d_in[19];
    const void* be2 = d_in[20];

    const int N = in_sizes[0] / 128;
    const int E = in_sizes[1] / 2;
    const int nPos = in_sizes[2] / 2;
    const int nNeg = in_sizes[3] / 2;
    const int nbuck = (N + 127) >> 7;
    const int nbuckP = (nbuck + 15) & ~15;     // pad rows to 64B
    const int EPB = 4096;                      // high-TLP CSR build grid
    const int B1 = (E + EPB - 1) / EPB;

    char* p = (char*)d_ws;
    auto alloc = [&](size_t bytes) -> void* {
        void* r = (void*)p;
        p += (bytes + 255) & ~(size_t)255;
        return r;
    };
    int*   flags     = (int*)alloc(64);
    int*   blockhist = (int*)alloc((size_t)B1 * nbuckP * 4);
    int*   coltot    = (int*)alloc((size_t)nbuck * 4);
    int*   bucketbase= (int*)alloc((size_t)nbuck * 4);
    int*   rowptr    = (int*)alloc((size_t)(N + 1) * 4);
    unsigned* pairs  = (unsigned*)alloc((size_t)E * 4);
    int*   colbuf    = (int*)alloc((size_t)E * 4);
    u16*   xb      = (u16*)alloc((size_t)N * 128 * 2);   // reused as hbufB
    u16*   hbufA   = (u16*)alloc((size_t)N * 128 * 2);   // reused as zbuf
    u16*   meanbuf = (u16*)alloc((size_t)N * 128 * 2);   // reused as ubuf
    u8*    x8      = (u8*)alloc((size_t)N * 128);
    u8*    h8      = (u8*)alloc((size_t)N * 128);
    u8*    t8      = (u8*)alloc((size_t)N * 64);
    u16*   Wcat1   = (u16*)alloc((size_t)256 * 128 * 2);
    u16*   Wcat2   = (u16*)alloc((size_t)256 * 128 * 2);
    u16*   Wcat3   = (u16*)alloc((size_t)128 * 128 * 2);
    u16*   Web     = (u16*)alloc((size_t)128 * 128 * 2);
    float* al1 = (float*)alloc(128 * 4);
    float* bt1 = (float*)alloc(128 * 4);
    float* al2 = (float*)alloc(128 * 4);
    float* bt2 = (float*)alloc(128 * 4);
    float* al3 = (float*)alloc(128 * 4);
    float* bt3 = (float*)alloc(128 * 4);
    float* dparams = (float*)alloc(260 * 4);
    u16* hbufB = xb;
    u16* ubuf  = meanbuf + (size_t)N * 64;   // meanbuf free after gemm2
    u16* zbuf  = hbufA + (size_t)N * 64;     // hbufA free after gemm2

    // dtype sniff + bucketed CSR build (no global atomics)
    sniff_kernel<<<1, 256, 0, stream>>>((const unsigned*)x, ei, flags);
    bucket_count_kernel<<<B1, 256, 0, stream>>>(ei, blockhist, E, EPB, nbuckP, nbuck, flags);
    colscan_kernel<<<nbuck, 64, 0, stream>>>(blockhist, coltot, B1, nbuckP);
    base_scan_kernel<<<1, 1024, 0, stream>>>(coltot, bucketbase, rowptr + N, nbuck, E);
    bucket_scatter_kernel<<<B1, 256, 0, stream>>>(ei, bucketbase, blockhist, pairs, E, EPB, nbuckP, nbuck, flags);
    bucket_csr_kernel<<<nbuck, 256, 0, stream>>>(pairs, bucketbase, coltot, rowptr, colbuf, N);

    // input / parameter conversion
    cvt_x_kernel<<<(N * 64 + 255) / 256, 256, 0, stream>>>(x, xb, (u16*)x8, flags, N * 64);
    prep_all_kernel<<<(66048 + 255) / 256, 256, 0, stream>>>(
        Wl1, Wr1, Wcat1, Wl2, Wr2, Wcat2, Wl3, Wr3, Wcat3, We1, Web,
        g1, b1, bl1, al1, bt1, g2, b2, bl2, al2, bt2, bl3, al3, bt3,
        be1, We2, be2, dparams, flags);

    int gB = (N + 63) / 64;
    size_t lds256 = (size_t)64 * 256 * 2;
    size_t lds128 = (size_t)64 * 128 * 2;

    // layer 1: mean from x8; h1 = relu(bn([mean|x]@W1)) + x -> hbufA (bf16) + h8 (fp8)
    aggregate_fp8_kernel<128><<<(N + 31) / 32, 256, 0, stream>>>(x8, rowptr, colbuf, meanbuf, N);
    gemm_sage_kernel<256><<<gB, 256, lds256, stream>>>(meanbuf, xb, Wcat1, al1, bt1,
                                                       1, hbufA, 128, nullptr, h8, 128, N, 1);
    // layer 2: mean from h8; h2 -> hbufB (bf16 only)
    aggregate_fp8_kernel<128><<<(N + 31) / 32, 256, 0, stream>>>(h8, rowptr, colbuf, meanbuf, N);
    gemm_sage_kernel<256><<<gB, 256, lds256, stream>>>(meanbuf, hbufA, Wcat2, al2, bt2,
                                                       1, hbufB, 128, nullptr, nullptr, 0, N, 1);
    // layer 3 (commuted): [t|u] = h2@[Wl3|Wr3]; t -> t8 (fp8), u -> ubuf (bf16)
    gemm_sage_kernel<128><<<gB, 256, lds128, stream>>>(hbufB, hbufB, Wcat3, al3, bt3,
                                                       0, nullptr, 0, ubuf, t8, 64, N, 0);
    // z = mean(t8) + u -> zbuf + d_out
    agg_combine_kernel<<<(N + 63) / 64, 256, 0, stream>>>(t8, rowptr, colbuf, ubuf, zbuf,
                                                          d_out, N, flags);

    // decode pos + neg in one launch (64 edges/block)
    long long posBase = (long long)N * 64;
    int bP = (nPos + 63) / 64, bN = (nNeg + 63) / 64;
    decode_kernel<<<bP + bN, 256, 0, stream>>>(zbuf, pos, neg, nPos, nNeg, bP,
                                               Web, dparams, d_out, posBase, flags);
}